// Round 7
// baseline (492.066 us; speedup 1.0000x reference)
//
#include <hip/hip_runtime.h>
#include <math.h>

// F_IN = HC = 256, H = 4, C = 64. N, E from in_sizes.

typedef float f32x4 __attribute__((ext_vector_type(4)));
typedef short s16x8 __attribute__((ext_vector_type(8)));

static __device__ __forceinline__ unsigned short f2bf(float f) {
    unsigned int u = __float_as_uint(f);
    unsigned int r = u + 0x7FFFu + ((u >> 16) & 1u);   // RNE
    return (unsigned short)(r >> 16);
}
static __device__ __forceinline__ float bf2f(unsigned short u) {
    return __uint_as_float(((unsigned int)u) << 16);
}
static __device__ __forceinline__ float blo(unsigned int u) {
    return __uint_as_float(u << 16);
}
static __device__ __forceinline__ float bhi(unsigned int u) {
    return __uint_as_float(u & 0xffff0000u);
}

#define LOG2E_8 0.18033688011112042f   // log2(e)/8

// ---------------------------------------------------------------------------
// W prep: LDS-tiled transpose. 64 blocks = 4 matrices x 16 (4x4) 64x64 tiles.
// wt[col 0..1023][k 0..255] bf16, bcat[1024] fp32. Coalesced both sides.
// ---------------------------------------------------------------------------
__global__ __launch_bounds__(256) void la_wprep2(
    const float* __restrict__ Wq, const float* __restrict__ Wk,
    const float* __restrict__ Wv, const float* __restrict__ Ws,
    const float* __restrict__ bq, const float* __restrict__ bk,
    const float* __restrict__ bv, const float* __restrict__ bs,
    unsigned short* __restrict__ wt, float* __restrict__ bcat)
{
    __shared__ float T[64][68];
    const int bid = blockIdx.x;
    const int m  = bid >> 4;
    const int kt = (bid >> 2) & 3, ct = bid & 3;
    const int k0 = kt * 64, c0 = ct * 64;
    const float* W = (m == 0) ? Wq : (m == 1) ? Wk : (m == 2) ? Wv : Ws;
    const float* B = (m == 0) ? bq : (m == 1) ? bk : (m == 2) ? bv : bs;
    const int t = threadIdx.x;

#pragma unroll
    for (int it = 0; it < 4; ++it) {
        int s = it * 256 + t;         // 0..1023
        int r = s >> 4;               // k-row in tile
        int q = (s & 15) * 4;         // col offset
        float4 v = *(const float4*)(W + (size_t)(k0 + r) * 256 + c0 + q);
        T[r][q + 0] = v.x; T[r][q + 1] = v.y;
        T[r][q + 2] = v.z; T[r][q + 3] = v.w;
    }
    __syncthreads();
#pragma unroll
    for (int it = 0; it < 4; ++it) {
        int s = it * 256 + t;
        int c = s >> 4;               // col in tile
        int kq = (s & 15) * 4;        // k offset
        ushort4 o;
        o.x = f2bf(T[kq + 0][c]); o.y = f2bf(T[kq + 1][c]);
        o.z = f2bf(T[kq + 2][c]); o.w = f2bf(T[kq + 3][c]);
        *(ushort4*)(wt + (size_t)(m * 256 + c0 + c) * 256 + k0 + kq) = o;
    }
    if (kt == 0 && t < 64) bcat[m * 256 + c0 + t] = B[c0 + t];
}

// ---------------------------------------------------------------------------
// MFMA GEMM v2: one block = 64 rows x all 1024 cols (8 panels of 128).
// A-panel (64x256 bf16) staged ONCE from fp32 x with on-the-fly convert;
// per panel, per 32-k step, Bs re-staged. Wave tile 32x64 (2x4 frags).
// Outputs: panel>>1 = 0 -> qarr, 1/2 -> kv packed, 3 -> skip.
// ---------------------------------------------------------------------------
__global__ __launch_bounds__(256) void la_gemm2(
    const float* __restrict__ x, const unsigned short* __restrict__ wt,
    const float* __restrict__ bcat,
    unsigned short* __restrict__ qarr, unsigned short* __restrict__ kv,
    unsigned short* __restrict__ skiparr, int n)
{
    __shared__ __align__(16) unsigned short As[64 * 264];
    __shared__ __align__(16) unsigned short Bs[128 * 40];

    const int row0 = blockIdx.x * 64;
    const int t = threadIdx.x;
    const int l = t & 63, w = t >> 6;
    const int wr = w & 1, wc = w >> 1;     // wave 32-row x 64-col tile
    const int l15 = l & 15, l4 = l >> 4;

    // stage A: 64 rows x 256 k, fp32 -> bf16
#pragma unroll
    for (int it = 0; it < 16; ++it) {
        int s = it * 256 + t;              // 0..4095
        int r = s >> 6;
        int q = (s & 63) * 4;
        int gr = row0 + r;
        float4 v = make_float4(0.f, 0.f, 0.f, 0.f);
        if (gr < n) v = *(const float4*)(x + (size_t)gr * 256 + q);
        ushort4 o;
        o.x = f2bf(v.x); o.y = f2bf(v.y); o.z = f2bf(v.z); o.w = f2bf(v.w);
        *(ushort4*)(As + r * 264 + q) = o;
    }
    __syncthreads();

    for (int p = 0; p < 8; ++p) {
        const int col0 = p * 128;
        const int msel = p >> 1;
        f32x4 acc[2][4];
#pragma unroll
        for (int i = 0; i < 2; ++i)
#pragma unroll
            for (int j = 0; j < 4; ++j) acc[i][j] = (f32x4){0.f, 0.f, 0.f, 0.f};

        for (int ks = 0; ks < 8; ++ks) {
            const int k0 = ks * 32;
#pragma unroll
            for (int it = 0; it < 2; ++it) {
                int s = it * 256 + t;      // 0..511
                int c = s >> 2;
                int ko = (s & 3) * 8;
                *(s16x8*)(Bs + c * 40 + ko) =
                    *(const s16x8*)(wt + (size_t)(col0 + c) * 256 + k0 + ko);
            }
            __syncthreads();
            s16x8 af[2], bfr[4];
#pragma unroll
            for (int f = 0; f < 2; ++f)
                af[f] = *(const s16x8*)(As + (wr * 32 + f * 16 + l15) * 264
                                        + k0 + l4 * 8);
#pragma unroll
            for (int f = 0; f < 4; ++f)
                bfr[f] = *(const s16x8*)(Bs + (wc * 64 + f * 16 + l15) * 40
                                         + l4 * 8);
#pragma unroll
            for (int fm = 0; fm < 2; ++fm)
#pragma unroll
                for (int fn = 0; fn < 4; ++fn)
                    acc[fm][fn] = __builtin_amdgcn_mfma_f32_16x16x32_bf16(
                        af[fm], bfr[fn], acc[fm][fn], 0, 0, 0);
            __syncthreads();
        }

        // epilogue for this panel
#pragma unroll
        for (int fm = 0; fm < 2; ++fm) {
#pragma unroll
            for (int fn = 0; fn < 4; ++fn) {
                int gc = col0 + wc * 64 + fn * 16 + l15;
                int c  = gc & 255;
                float bb = bcat[gc];
#pragma unroll
                for (int j = 0; j < 4; ++j) {
                    int gr = row0 + wr * 32 + fm * 16 + l4 * 4 + j;
                    if (gr >= n) continue;
                    unsigned short val = f2bf(acc[fm][fn][j] + bb);
                    if (msel == 0) {
                        qarr[(size_t)gr * 256 + c] = val;
                    } else if (msel == 3) {
                        skiparr[(size_t)gr * 256 + c] = val;
                    } else {
                        int hh = c >> 6, ch = c & 63;
                        size_t idx = (size_t)gr * 512 + hh * 128 + (ch >> 2) * 8
                                   + (ch & 3) + ((msel == 2) ? 4 : 0);
                        kv[idx] = val;
                    }
                }
            }
        }
    }
}

// ---------------------------------------------------------------------------
// CSR build: histogram, 3-phase parallel scan, scatter (packed 8B records).
// ---------------------------------------------------------------------------
__global__ void la_hist(const int* __restrict__ dst, int e, int* __restrict__ deg)
{
    int i = blockIdx.x * blockDim.x + threadIdx.x;
    int stride = gridDim.x * blockDim.x;
    for (; i < e; i += stride) atomicAdd(&deg[dst[i]], 1);
}

__global__ void la_chunksum(const int* __restrict__ deg, int n, int* __restrict__ part)
{
    int b = blockIdx.x, t = threadIdx.x;
    int i = b * 256 + t;
    int v = (i < n) ? deg[i] : 0;
#pragma unroll
    for (int mask = 32; mask >= 1; mask >>= 1) v += __shfl_xor(v, mask);
    __shared__ int ws[4];
    if ((t & 63) == 0) ws[t >> 6] = v;
    __syncthreads();
    if (t == 0) part[b] = ws[0] + ws[1] + ws[2] + ws[3];
}

__global__ void la_scanpart(int* __restrict__ part, int nb)   // nb <= 256
{
    __shared__ int s[256];
    int t = threadIdx.x;
    int v = (t < nb) ? part[t] : 0;
    int orig = v;
    s[t] = v;
    __syncthreads();
    for (int o = 1; o < 256; o <<= 1) {
        int u = (t >= o) ? s[t - o] : 0;
        __syncthreads();
        s[t] += u;
        __syncthreads();
    }
    if (t < nb) part[t] = s[t] - orig;   // exclusive
}

__global__ void la_scanfinal(const int* __restrict__ deg, int n,
                             const int* __restrict__ part, int* __restrict__ offs,
                             int* __restrict__ cursor, int e)
{
    int b = blockIdx.x, t = threadIdx.x;
    int i = b * 256 + t;
    int d = (i < n) ? deg[i] : 0;
    int v = d;
#pragma unroll
    for (int o = 1; o < 64; o <<= 1) {
        int u = __shfl_up(v, o);
        if ((t & 63) >= o) v += u;
    }
    __shared__ int wt[4];
    if ((t & 63) == 63) wt[t >> 6] = v;
    __syncthreads();
    int add = 0;
    for (int wv = 0; wv < (t >> 6); ++wv) add += wt[wv];
    int excl = v + add - d + part[b];
    if (i < n) { offs[i] = excl; cursor[i] = excl; }
    if (b == 0 && t == 0) offs[n] = e;
}

__global__ void la_scatter(const int* __restrict__ src, const int* __restrict__ dst,
                           const float* __restrict__ ea, int e,
                           int* __restrict__ cursor, uint2* __restrict__ rec)
{
    int i = blockIdx.x * blockDim.x + threadIdx.x;
    int stride = gridDim.x * blockDim.x;
    for (; i < e; i += stride) {
        int d = dst[i];
        int pos = atomicAdd(&cursor[d], 1);
        rec[pos] = make_uint2((unsigned int)src[i], __float_as_uint(ea[i]));
    }
}

// ---------------------------------------------------------------------------
// Attention v3: block = node, wave = head. 4 edges/wave-iter (16-lane
// quarters), 4 channels/lane, one dwordx4 kv gather per lane per edge.
// Writes outb as bf16.
// ---------------------------------------------------------------------------
__global__ __launch_bounds__(256) void la_attn3(
    const unsigned short* __restrict__ qarr,
    const unsigned short* __restrict__ kv,
    const unsigned short* __restrict__ skiparr,
    const uint2* __restrict__ rec,
    const int* __restrict__ offs,
    const float* __restrict__ We, const float* __restrict__ be,
    unsigned short* __restrict__ outb)
{
    const int node = blockIdx.x;
    const int t = threadIdx.x;
    const int h = t >> 6;
    const int l = t & 63;
    const int quarter = l >> 4;
    const int lc = l & 15;
    const int cb = h * 64 + lc * 4;     // channel base (4 per lane)

    uint2 qp = *(const uint2*)(qarr + (size_t)node * 256 + cb);
    const float q0 = blo(qp.x), q1 = bhi(qp.x);
    const float q2 = blo(qp.y), q3 = bhi(qp.y);
    float4 we4 = *(const float4*)(We + cb);
    float4 be4 = *(const float4*)(be + cb);

    float pw = fmaf(q3, we4.w, fmaf(q2, we4.z, fmaf(q1, we4.y, q0 * we4.x)));
    float pb = fmaf(q3, be4.w, fmaf(q2, be4.z, fmaf(q1, be4.y, q0 * be4.x)));
#pragma unroll
    for (int mask = 1; mask <= 8; mask <<= 1) {
        pw += __shfl_xor(pw, mask);
        pb += __shfl_xor(pb, mask);
    }
    const float qWe8 = pw * LOG2E_8;
    const float qbe8 = pb * LOG2E_8;

    const int start = offs[node], end = offs[node + 1];
    const int koff = h * 128 + lc * 8;

    float lsum = 0.f, Sfa = 0.f;
    float a0 = 0.f, a1 = 0.f, a2 = 0.f, a3 = 0.f;

    for (int j0 = start; j0 < end; j0 += 4) {
        int j = j0 + quarter;
        bool valid = (j < end);
        int jj = valid ? j : j0;
        uint2 r = rec[jj];
        int   s   = (int)r.x;
        float eaj = __uint_as_float(r.y);
        uint4 kvu = *(const uint4*)(kv + (((size_t)s) << 9) + koff);
        float k0 = blo(kvu.x), k1 = bhi(kvu.x);
        float k2 = blo(kvu.y), k3 = bhi(kvu.y);
        float d = fmaf(q3, k3, fmaf(q2, k2, fmaf(q1, k1, q0 * k0)));
#pragma unroll
        for (int mask = 1; mask <= 8; mask <<= 1) d += __shfl_xor(d, mask);
        float aL = fmaf(d, LOG2E_8, fmaf(eaj, qWe8, qbe8));
        aL = valid ? aL : -INFINITY;
        float f = exp2f(aL);
        lsum += f;
        Sfa = fmaf(f, eaj, Sfa);
        float v0 = blo(kvu.z), v1 = bhi(kvu.z);
        float v2 = blo(kvu.w), v3 = bhi(kvu.w);
        a0 = fmaf(f, v0, a0);
        a1 = fmaf(f, v1, a1);
        a2 = fmaf(f, v2, a2);
        a3 = fmaf(f, v3, a3);
    }

#pragma unroll
    for (int mask = 16; mask <= 32; mask <<= 1) {
        lsum += __shfl_xor(lsum, mask);
        Sfa  += __shfl_xor(Sfa,  mask);
        a0   += __shfl_xor(a0,   mask);
        a1   += __shfl_xor(a1,   mask);
        a2   += __shfl_xor(a2,   mask);
        a3   += __shfl_xor(a3,   mask);
    }

    if (quarter == 0) {
        float inv = 1.f / (lsum + 1e-16f);
        uint2 sp = *(const uint2*)(skiparr + (size_t)node * 256 + cb);
        ushort4 o;
        o.x = f2bf(fmaf(we4.x, Sfa, fmaf(be4.x, lsum, a0)) * inv + blo(sp.x));
        o.y = f2bf(fmaf(we4.y, Sfa, fmaf(be4.y, lsum, a1)) * inv + bhi(sp.x));
        o.z = f2bf(fmaf(we4.z, Sfa, fmaf(be4.z, lsum, a2)) * inv + blo(sp.y));
        o.w = f2bf(fmaf(we4.w, Sfa, fmaf(be4.w, lsum, a3)) * inv + bhi(sp.y));
        *(ushort4*)(outb + (size_t)node * 256 + cb) = o;
    }
}

// ---------------------------------------------------------------------------
// GraphNorm column sums (bf16 input).
// ---------------------------------------------------------------------------
__global__ __launch_bounds__(256) void la_colsum(
    const unsigned short* __restrict__ outb, float* __restrict__ cs,
    float* __restrict__ cs2, int n)
{
    const int col = threadIdx.x;
    const int r0 = blockIdx.x * 64;
    const int rend = (r0 + 64 < n) ? r0 + 64 : n;
    float s = 0.f, s2 = 0.f;
    for (int r = r0; r < rend; ++r) {
        float vv = bf2f(outb[(size_t)r * 256 + col]);
        s += vv;
        s2 = fmaf(vv, vv, s2);
    }
    atomicAdd(&cs[col], s);
    atomicAdd(&cs2[col], s2);
}

// ---------------------------------------------------------------------------
// Gram via MFMA (bf16 input, in-block GraphNorm coeffs): xt = R^T R,
// R = relu(out*A + B). Grid = 3*KSPLIT; tile = bx%3: 0=(0,0), 1=(0,128)
// mirrored, 2=(128,128). LDS dword-packed k-pairs, XOR swizzle.
// ---------------------------------------------------------------------------
__global__ __launch_bounds__(256) void la_gram_mfma(
    const unsigned short* __restrict__ outb,
    const float* __restrict__ cs, const float* __restrict__ cs2,
    const float* __restrict__ gnw, const float* __restrict__ gnb,
    const float* __restrict__ gms,
    float* __restrict__ xt, int n, int kchunk)
{
    __shared__ __align__(16) unsigned int Ta[128 * 20];
    __shared__ __align__(16) unsigned int Tb[128 * 20];

    const int bx = blockIdx.x;
    const int kc   = bx / 3;
    const int tile = bx - kc * 3;              // 0,1,2
    const int i0 = (tile == 2) ? 128 : 0;
    const int j0 = (tile == 0) ? 0 : 128;
    const bool diag = (tile != 1);
    const int kbeg = kc * kchunk;
    if (kbeg >= n) return;
    const int kend = (kbeg + kchunk < n) ? kbeg + kchunk : n;

    const int t = threadIdx.x;
    const int l = t & 63, w = t >> 6;
    const int wr = w >> 1, wc = w & 1;
    const int l15 = l & 15, l4 = l >> 4;

    const int kp  = t >> 4;    // 0..15 : k-pair
    const int cg8 = t & 15;    // cols cg8*8 .. +7

    const float invn = 1.f / (float)n;
    float Ai[8], Bi[8], Aj[8], Bj[8];
#pragma unroll
    for (int j = 0; j < 8; ++j) {
        {
            int ci = i0 + cg8 * 8 + j;
            float mean = cs[ci] * invn;
            float m2   = cs2[ci] * invn;
            float s    = gms[ci];
            float var  = m2 - 2.f * s * mean * mean + s * s * mean * mean;
            float a    = gnw[ci] / sqrtf(var + 1e-5f);
            Ai[j] = a; Bi[j] = gnb[ci] - s * mean * a;
        }
        {
            int cj = j0 + cg8 * 8 + j;
            float mean = cs[cj] * invn;
            float m2   = cs2[cj] * invn;
            float s    = gms[cj];
            float var  = m2 - 2.f * s * mean * mean + s * s * mean * mean;
            float a    = gnw[cj] / sqrtf(var + 1e-5f);
            Aj[j] = a; Bj[j] = gnb[cj] - s * mean * a;
        }
    }

    f32x4 acc[4][4];
#pragma unroll
    for (int i = 0; i < 4; ++i)
#pragma unroll
        for (int j = 0; j < 4; ++j) acc[i][j] = (f32x4){0.f, 0.f, 0.f, 0.f};

    const int nsteps = (kend - kbeg + 31) >> 5;
    for (int ks = 0; ks < nsteps; ++ks) {
        const int gr0 = kbeg + ks * 32 + kp * 2;
        const bool v0 = (gr0 < kend), v1 = (gr0 + 1 < kend);

        {
            uint4 u0 = make_uint4(0,0,0,0), u1 = make_uint4(0,0,0,0);
            if (v0) u0 = *(const uint4*)(outb + (size_t)gr0 * 256 + i0 + cg8 * 8);
            if (v1) u1 = *(const uint4*)(outb + (size_t)(gr0+1) * 256 + i0 + cg8 * 8);
            float xs[8] = {blo(u0.x),bhi(u0.x),blo(u0.y),bhi(u0.y),
                           blo(u0.z),bhi(u0.z),blo(u0.w),bhi(u0.w)};
            float ys[8] = {blo(u1.x),bhi(u1.x),blo(u1.y),bhi(u1.y),
                           blo(u1.z),bhi(u1.z),blo(u1.w),bhi(u1.w)};
#pragma unroll
            for (int j = 0; j < 8; ++j) {
                float r0 = v0 ? fmaxf(fmaf(xs[j], Ai[j], Bi[j]), 0.f) : 0.f;
                float r1 = v1 ? fmaxf(fmaf(ys[j], Ai[j], Bi[j]), 0.f) : 0.f;
                int c = cg8 * 8 + j;
                unsigned int u = (unsigned int)f2bf(r0)
                               | ((unsigned int)f2bf(r1) << 16);
                Ta[c * 20 + (kp ^ (((c >> 3) & 3) << 2))] = u;
            }
        }
        if (!diag) {
            uint4 u0 = make_uint4(0,0,0,0), u1 = make_uint4(0,0,0,0);
            if (v0) u0 = *(const uint4*)(outb + (size_t)gr0 * 256 + j0 + cg8 * 8);
            if (v1) u1 = *(const uint4*)(outb + (size_t)(gr0+1) * 256 + j0 + cg8 * 8);
            float xs[8] = {blo(u0.x),bhi(u0.x),blo(u0.y),bhi(u0.y),
                           blo(u0.z),bhi(u0.z),blo(u0.w),bhi(u0.w)};
            float ys[8] = {blo(u1.x),bhi(u1.x),blo(u1.y),bhi(u1.y),
                           blo(u1.z),bhi(u1.z),blo(u1.w),bhi(u1.w)};
#pragma unroll
            for (int j = 0; j < 8; ++j) {
                float r0 = v0 ? fmaxf(fmaf(xs[j], Aj[j], Bj[j]), 0.f) : 0.f;
                float r1 = v1 ? fmaxf(fmaf(ys[j], Aj[j], Bj[j]), 0.f) : 0.f;
                int c = cg8 * 8 + j;
                unsigned int u = (unsigned int)f2bf(r0)
                               | ((unsigned int)f2bf(r1) << 16);
                Tb[c * 20 + (kp ^ (((c >> 3) & 3) << 2))] = u;
            }
        }
        __syncthreads();

        const unsigned int* TB = diag ? Ta : Tb;
        s16x8 af[4], bfr[4];
#pragma unroll
        for (int f = 0; f < 4; ++f) {
            int ca = wr * 64 + f * 16 + l15;
            af[f] = *(const s16x8*)(Ta + ca * 20 + ((l4 * 4) ^ (((ca >> 3) & 3) << 2)));
            int cb2 = wc * 64 + f * 16 + l15;
            bfr[f] = *(const s16x8*)(TB + cb2 * 20 + ((l4 * 4) ^ (((cb2 >> 3) & 3) << 2)));
        }
#pragma unroll
        for (int fm = 0; fm < 4; ++fm)
#pragma unroll
            for (int fn = 0; fn < 4; ++fn)
                acc[fm][fn] = __builtin_amdgcn_mfma_f32_16x16x32_bf16(
                    af[fm], bfr[fn], acc[fm][fn], 0, 0, 0);
        __syncthreads();
    }

#pragma unroll
    for (int fm = 0; fm < 4; ++fm)
#pragma unroll
        for (int fn = 0; fn < 4; ++fn) {
            int col = j0 + wc * 64 + fn * 16 + l15;
#pragma unroll
            for (int j = 0; j < 4; ++j) {
                int row = i0 + wr * 64 + fm * 16 + l4 * 4 + j;
                float vv = acc[fm][fn][j];
                atomicAdd(&xt[(size_t)row * 256 + col], vv);
                if (tile == 1)
                    atomicAdd(&xt[(size_t)col * 256 + row], vv);
            }
        }
}

// ---------------------------------------------------------------------------
// min/max partials (32 blocks), final reduce folded into la_norm prologue.
// ---------------------------------------------------------------------------
__global__ __launch_bounds__(256) void la_minmax_part(
    const float* __restrict__ xt, float* __restrict__ mmp)
{
    const int b = blockIdx.x, t = threadIdx.x;
    float mn = INFINITY, mx = -INFINITY;
#pragma unroll
    for (int k = 0; k < 2; ++k) {
        float4 v = ((const float4*)xt)[b * 512 + k * 256 + t];
        mn = fminf(mn, fminf(fminf(v.x, v.y), fminf(v.z, v.w)));
        mx = fmaxf(mx, fmaxf(fmaxf(v.x, v.y), fmaxf(v.z, v.w)));
    }
#pragma unroll
    for (int mask = 32; mask >= 1; mask >>= 1) {
        mn = fminf(mn, __shfl_xor(mn, mask));
        mx = fmaxf(mx, __shfl_xor(mx, mask));
    }
    __shared__ float smn[4], smx[4];
    if ((t & 63) == 0) { smn[t >> 6] = mn; smx[t >> 6] = mx; }
    __syncthreads();
    if (t == 0) {
        mn = fminf(fminf(smn[0], smn[1]), fminf(smn[2], smn[3]));
        mx = fmaxf(fmaxf(smx[0], smx[1]), fmaxf(smx[2], smx[3]));
        mmp[b * 2]     = mn;
        mmp[b * 2 + 1] = mx;
    }
}

__global__ void la_norm(float* __restrict__ xt, const float* __restrict__ mmp)
{
    float mn = INFINITY, mx = -INFINITY;
#pragma unroll
    for (int i = 0; i < 32; ++i) {
        mn = fminf(mn, mmp[i * 2]);
        mx = fmaxf(mx, mmp[i * 2 + 1]);
    }
    float inv = 1.f / (mx - mn + 1e-8f);
    int i = blockIdx.x * blockDim.x + threadIdx.x;
    xt[i] = (xt[i] - mn) * inv;
}

// ---------------------------------------------------------------------------
extern "C" void kernel_launch(void* const* d_in, const int* in_sizes, int n_in,
                              void* d_out, int out_size, void* d_ws, size_t ws_size,
                              hipStream_t stream)
{
    const float* x   = (const float*)d_in[0];
    const int*   ei  = (const int*)  d_in[1];
    const float* ea  = (const float*)d_in[2];
    const float* Wq  = (const float*)d_in[3];
    const float* bq  = (const float*)d_in[4];
    const float* Wk  = (const float*)d_in[5];
    const float* bk  = (const float*)d_in[6];
    const float* Wv  = (const float*)d_in[7];
    const float* bv  = (const float*)d_in[8];
    const float* We  = (const float*)d_in[9];
    const float* be  = (const float*)d_in[10];
    const float* Ws  = (const float*)d_in[11];
    const float* bs  = (const float*)d_in[12];
    const float* gnw = (const float*)d_in[13];
    const float* gnb = (const float*)d_in[14];
    const float* gms = (const float*)d_in[15];

    const int n = in_sizes[0] / 256;
    const int e = in_sizes[1] / 2;
    const int* srcI = ei;
    const int* dstI = ei + e;

    char* ws = (char*)d_ws;
    size_t off = 0;
    auto take = [&](size_t bytes) -> void* {
        void* p = (void*)(ws + off);
        off += (bytes + 255) & ~(size_t)255;
        return p;
    };
    unsigned short* wtbuf = (unsigned short*)take((size_t)1024 * 256 * 2);
    float*          bcat  = (float*)take(1024 * 4);
    unsigned short* qarr  = (unsigned short*)take((size_t)n * 256 * 2);
    unsigned short* kv    = (unsigned short*)take((size_t)n * 512 * 2);
    unsigned short* skipb = (unsigned short*)take((size_t)n * 256 * 2);
    unsigned short* outb  = (unsigned short*)take((size_t)n * 256 * 2);
    int*   deg    = (int*)  take((size_t)n * 4);
    int*   cursor = (int*)  take((size_t)n * 4);
    int*   offs   = (int*)  take((size_t)(n + 1) * 4);
    int*   part   = (int*)  take(256 * 4);
    uint2* csrR   = (uint2*)take((size_t)e * 8);
    float* cs     = (float*)take(256 * 4);
    float* cs2    = (float*)take(256 * 4);
    float* mmp    = (float*)take(64 * 4);
    (void)ws_size; (void)n_in; (void)out_size;

    float* xt = (float*)d_out;

    hipMemsetAsync(deg, 0, (size_t)n * 4, stream);
    hipMemsetAsync(cs,  0, 256 * 4, stream);
    hipMemsetAsync(cs2, 0, 256 * 4, stream);
    hipMemsetAsync(xt,  0, (size_t)65536 * 4, stream);

    la_wprep2<<<64, 256, 0, stream>>>(Wq, Wk, Wv, Ws, bq, bk, bv, bs, wtbuf, bcat);
    la_gemm2 <<<(n + 63) / 64, 256, 0, stream>>>(x, wtbuf, bcat,
                                                 qarr, kv, skipb, n);

    const int nchunk = (n + 255) / 256;
    la_hist     <<<1024, 256, 0, stream>>>(dstI, e, deg);
    la_chunksum <<<nchunk, 256, 0, stream>>>(deg, n, part);
    la_scanpart <<<1, 256, 0, stream>>>(part, nchunk);
    la_scanfinal<<<nchunk, 256, 0, stream>>>(deg, n, part, offs, cursor, e);
    la_scatter  <<<1024, 256, 0, stream>>>(srcI, dstI, ea, e, cursor, csrR);

    la_attn3<<<n, 256, 0, stream>>>(qarr, kv, skipb, csrR, offs, We, be, outb);

    la_colsum<<<(n + 63) / 64, 256, 0, stream>>>(outb, cs, cs2, n);

    const int KSPLIT = 64;
    int kchunk = ((n + KSPLIT - 1) / KSPLIT + 31) & ~31;
    la_gram_mfma<<<3 * KSPLIT, 256, 0, stream>>>(outb, cs, cs2, gnw, gnb, gms,
                                                 xt, n, kchunk);

    la_minmax_part<<<32, 256, 0, stream>>>(xt, mmp);
    la_norm<<<256, 256, 0, stream>>>(xt, mmp);
}

// Round 8
// 460.508 us; speedup vs baseline: 1.0685x; 1.0685x over previous
//
#include <hip/hip_runtime.h>
#include <math.h>

// F_IN = HC = 256, H = 4, C = 64. N, E from in_sizes.

typedef float f32x4 __attribute__((ext_vector_type(4)));
typedef short s16x8 __attribute__((ext_vector_type(8)));

static __device__ __forceinline__ unsigned short f2bf(float f) {
    unsigned int u = __float_as_uint(f);
    unsigned int r = u + 0x7FFFu + ((u >> 16) & 1u);   // RNE
    return (unsigned short)(r >> 16);
}
static __device__ __forceinline__ float bf2f(unsigned short u) {
    return __uint_as_float(((unsigned int)u) << 16);
}
static __device__ __forceinline__ float blo(unsigned int u) {
    return __uint_as_float(u << 16);
}
static __device__ __forceinline__ float bhi(unsigned int u) {
    return __uint_as_float(u & 0xffff0000u);
}

#define LOG2E_8 0.18033688011112042f   // log2(e)/8

// ---------------------------------------------------------------------------
// x (fp32 [n][256]) -> xb (bf16). x is L3-resident; this pass is cheap and
// the GEMM's 8x panel re-reads of bf16 xb are L3 hits.
// ---------------------------------------------------------------------------
__global__ void la_x2bf(const float* __restrict__ x, unsigned short* __restrict__ xb,
                        int total4)
{
    int i = blockIdx.x * blockDim.x + threadIdx.x;
    int stride = gridDim.x * blockDim.x;
    for (; i < total4; i += stride) {
        float4 v = ((const float4*)x)[i];
        ushort4 o;
        o.x = f2bf(v.x); o.y = f2bf(v.y); o.z = f2bf(v.z); o.w = f2bf(v.w);
        ((ushort4*)xb)[i] = o;
    }
}

// ---------------------------------------------------------------------------
// W prep: LDS-tiled transpose, coalesced both sides.
// ---------------------------------------------------------------------------
__global__ __launch_bounds__(256) void la_wprep2(
    const float* __restrict__ Wq, const float* __restrict__ Wk,
    const float* __restrict__ Wv, const float* __restrict__ Ws,
    const float* __restrict__ bq, const float* __restrict__ bk,
    const float* __restrict__ bv, const float* __restrict__ bs,
    unsigned short* __restrict__ wt, float* __restrict__ bcat)
{
    __shared__ float T[64][68];
    const int bid = blockIdx.x;
    const int m  = bid >> 4;
    const int kt = (bid >> 2) & 3, ct = bid & 3;
    const int k0 = kt * 64, c0 = ct * 64;
    const float* W = (m == 0) ? Wq : (m == 1) ? Wk : (m == 2) ? Wv : Ws;
    const float* B = (m == 0) ? bq : (m == 1) ? bk : (m == 2) ? bv : bs;
    const int t = threadIdx.x;

#pragma unroll
    for (int it = 0; it < 4; ++it) {
        int s = it * 256 + t;
        int r = s >> 4;
        int q = (s & 15) * 4;
        float4 v = *(const float4*)(W + (size_t)(k0 + r) * 256 + c0 + q);
        T[r][q + 0] = v.x; T[r][q + 1] = v.y;
        T[r][q + 2] = v.z; T[r][q + 3] = v.w;
    }
    __syncthreads();
#pragma unroll
    for (int it = 0; it < 4; ++it) {
        int s = it * 256 + t;
        int c = s >> 4;
        int kq = (s & 15) * 4;
        ushort4 o;
        o.x = f2bf(T[kq + 0][c]); o.y = f2bf(T[kq + 1][c]);
        o.z = f2bf(T[kq + 2][c]); o.w = f2bf(T[kq + 3][c]);
        *(ushort4*)(wt + (size_t)(m * 256 + c0 + c) * 256 + k0 + kq) = o;
    }
    if (kt == 0 && t < 64) bcat[m * 256 + c0 + t] = B[c0 + t];
}

// ---------------------------------------------------------------------------
// MFMA GEMM (R6 shape): 128x128 tile, 4 waves each 64x64 (4x4 frags).
// Grid (n/128, 8). Outputs: msel 0 qarr, 1/2 kv packed, 3 skip.
// ---------------------------------------------------------------------------
__global__ __launch_bounds__(256) void la_gemm_mfma(
    const unsigned short* __restrict__ xb, const unsigned short* __restrict__ wt,
    const float* __restrict__ bcat,
    unsigned short* __restrict__ qarr, unsigned short* __restrict__ kv,
    unsigned short* __restrict__ skiparr, int n)
{
    __shared__ __align__(16) unsigned short As[128 * 40];
    __shared__ __align__(16) unsigned short Bs[128 * 40];

    const int row0 = blockIdx.x * 128;
    const int col0 = blockIdx.y * 128;
    const int msel = blockIdx.y >> 1;
    const int t = threadIdx.x;
    const int l = t & 63;
    const int w = t >> 6;
    const int wr = w >> 1, wc = w & 1;
    const int l15 = l & 15, l4 = l >> 4;

    f32x4 acc[4][4];
#pragma unroll
    for (int i = 0; i < 4; ++i)
#pragma unroll
        for (int j = 0; j < 4; ++j) acc[i][j] = (f32x4){0.f, 0.f, 0.f, 0.f};

    for (int k0 = 0; k0 < 256; k0 += 32) {
#pragma unroll
        for (int c2 = 0; c2 < 2; ++c2) {
            int chunk = t + c2 * 256;
            int r  = chunk >> 2;
            int ko = (chunk & 3) * 8;
            int ga = row0 + r;
            s16x8 va = (s16x8){0,0,0,0,0,0,0,0};
            if (ga < n) va = *(const s16x8*)(xb + (size_t)ga * 256 + k0 + ko);
            *(s16x8*)(As + r * 40 + ko) = va;
            int gb = col0 + r;
            s16x8 vb = *(const s16x8*)(wt + (size_t)gb * 256 + k0 + ko);
            *(s16x8*)(Bs + r * 40 + ko) = vb;
        }
        __syncthreads();
        s16x8 af[4], bfr[4];
#pragma unroll
        for (int f = 0; f < 4; ++f) {
            af[f]  = *(const s16x8*)(As + (wr * 64 + f * 16 + l15) * 40 + l4 * 8);
            bfr[f] = *(const s16x8*)(Bs + (wc * 64 + f * 16 + l15) * 40 + l4 * 8);
        }
#pragma unroll
        for (int fm = 0; fm < 4; ++fm)
#pragma unroll
            for (int fn = 0; fn < 4; ++fn)
                acc[fm][fn] = __builtin_amdgcn_mfma_f32_16x16x32_bf16(
                    af[fm], bfr[fn], acc[fm][fn], 0, 0, 0);
        __syncthreads();
    }

#pragma unroll
    for (int fm = 0; fm < 4; ++fm) {
#pragma unroll
        for (int fn = 0; fn < 4; ++fn) {
            int gc = col0 + wc * 64 + fn * 16 + l15;
            int c  = gc & 255;
            float bb = bcat[gc];
#pragma unroll
            for (int j = 0; j < 4; ++j) {
                int gr = row0 + wr * 64 + fm * 16 + l4 * 4 + j;
                if (gr >= n) continue;
                unsigned short val = f2bf(acc[fm][fn][j] + bb);
                if (msel == 0) {
                    qarr[(size_t)gr * 256 + c] = val;
                } else if (msel == 3) {
                    skiparr[(size_t)gr * 256 + c] = val;
                } else {
                    int hh = c >> 6, ch = c & 63;
                    size_t idx = (size_t)gr * 512 + hh * 128 + (ch >> 2) * 8
                               + (ch & 3) + ((msel == 2) ? 4 : 0);
                    kv[idx] = val;
                }
            }
        }
    }
}

// ---------------------------------------------------------------------------
// CSR build: histogram, 3-phase parallel scan, scatter (packed 8B records).
// ---------------------------------------------------------------------------
__global__ void la_hist(const int* __restrict__ dst, int e, int* __restrict__ deg)
{
    int i = blockIdx.x * blockDim.x + threadIdx.x;
    int stride = gridDim.x * blockDim.x;
    for (; i < e; i += stride) atomicAdd(&deg[dst[i]], 1);
}

__global__ void la_chunksum(const int* __restrict__ deg, int n, int* __restrict__ part)
{
    int b = blockIdx.x, t = threadIdx.x;
    int i = b * 256 + t;
    int v = (i < n) ? deg[i] : 0;
#pragma unroll
    for (int mask = 32; mask >= 1; mask >>= 1) v += __shfl_xor(v, mask);
    __shared__ int ws[4];
    if ((t & 63) == 0) ws[t >> 6] = v;
    __syncthreads();
    if (t == 0) part[b] = ws[0] + ws[1] + ws[2] + ws[3];
}

__global__ void la_scanpart(int* __restrict__ part, int nb)   // nb <= 256
{
    __shared__ int s[256];
    int t = threadIdx.x;
    int v = (t < nb) ? part[t] : 0;
    int orig = v;
    s[t] = v;
    __syncthreads();
    for (int o = 1; o < 256; o <<= 1) {
        int u = (t >= o) ? s[t - o] : 0;
        __syncthreads();
        s[t] += u;
        __syncthreads();
    }
    if (t < nb) part[t] = s[t] - orig;   // exclusive
}

__global__ void la_scanfinal(const int* __restrict__ deg, int n,
                             const int* __restrict__ part, int* __restrict__ offs,
                             int* __restrict__ cursor, int e)
{
    int b = blockIdx.x, t = threadIdx.x;
    int i = b * 256 + t;
    int d = (i < n) ? deg[i] : 0;
    int v = d;
#pragma unroll
    for (int o = 1; o < 64; o <<= 1) {
        int u = __shfl_up(v, o);
        if ((t & 63) >= o) v += u;
    }
    __shared__ int wt[4];
    if ((t & 63) == 63) wt[t >> 6] = v;
    __syncthreads();
    int add = 0;
    for (int wv = 0; wv < (t >> 6); ++wv) add += wt[wv];
    int excl = v + add - d + part[b];
    if (i < n) { offs[i] = excl; cursor[i] = excl; }
    if (b == 0 && t == 0) offs[n] = e;
}

__global__ void la_scatter(const int* __restrict__ src, const int* __restrict__ dst,
                           const float* __restrict__ ea, int e,
                           int* __restrict__ cursor, uint2* __restrict__ rec)
{
    int i = blockIdx.x * blockDim.x + threadIdx.x;
    int stride = gridDim.x * blockDim.x;
    for (; i < e; i += stride) {
        int d = dst[i];
        int pos = atomicAdd(&cursor[d], 1);
        rec[pos] = make_uint2((unsigned int)src[i], __float_as_uint(ea[i]));
    }
}

// ---------------------------------------------------------------------------
// Attention v3: block = node, wave = head. 4 edges/wave-iter (16-lane
// quarters), 4 channels/lane, one dwordx4 kv gather per lane per edge.
// Writes outb as bf16.
// ---------------------------------------------------------------------------
__global__ __launch_bounds__(256) void la_attn3(
    const unsigned short* __restrict__ qarr,
    const unsigned short* __restrict__ kv,
    const unsigned short* __restrict__ skiparr,
    const uint2* __restrict__ rec,
    const int* __restrict__ offs,
    const float* __restrict__ We, const float* __restrict__ be,
    unsigned short* __restrict__ outb)
{
    const int node = blockIdx.x;
    const int t = threadIdx.x;
    const int h = t >> 6;
    const int l = t & 63;
    const int quarter = l >> 4;
    const int lc = l & 15;
    const int cb = h * 64 + lc * 4;     // channel base (4 per lane)

    uint2 qp = *(const uint2*)(qarr + (size_t)node * 256 + cb);
    const float q0 = blo(qp.x), q1 = bhi(qp.x);
    const float q2 = blo(qp.y), q3 = bhi(qp.y);
    float4 we4 = *(const float4*)(We + cb);
    float4 be4 = *(const float4*)(be + cb);

    float pw = fmaf(q3, we4.w, fmaf(q2, we4.z, fmaf(q1, we4.y, q0 * we4.x)));
    float pb = fmaf(q3, be4.w, fmaf(q2, be4.z, fmaf(q1, be4.y, q0 * be4.x)));
#pragma unroll
    for (int mask = 1; mask <= 8; mask <<= 1) {
        pw += __shfl_xor(pw, mask);
        pb += __shfl_xor(pb, mask);
    }
    const float qWe8 = pw * LOG2E_8;
    const float qbe8 = pb * LOG2E_8;

    const int start = offs[node], end = offs[node + 1];
    const int koff = h * 128 + lc * 8;

    float lsum = 0.f, Sfa = 0.f;
    float a0 = 0.f, a1 = 0.f, a2 = 0.f, a3 = 0.f;

    for (int j0 = start; j0 < end; j0 += 4) {
        int j = j0 + quarter;
        bool valid = (j < end);
        int jj = valid ? j : j0;
        uint2 r = rec[jj];
        int   s   = (int)r.x;
        float eaj = __uint_as_float(r.y);
        uint4 kvu = *(const uint4*)(kv + (((size_t)s) << 9) + koff);
        float k0 = blo(kvu.x), k1 = bhi(kvu.x);
        float k2 = blo(kvu.y), k3 = bhi(kvu.y);
        float d = fmaf(q3, k3, fmaf(q2, k2, fmaf(q1, k1, q0 * k0)));
#pragma unroll
        for (int mask = 1; mask <= 8; mask <<= 1) d += __shfl_xor(d, mask);
        float aL = fmaf(d, LOG2E_8, fmaf(eaj, qWe8, qbe8));
        aL = valid ? aL : -INFINITY;
        float f = exp2f(aL);
        lsum += f;
        Sfa = fmaf(f, eaj, Sfa);
        float v0 = blo(kvu.z), v1 = bhi(kvu.z);
        float v2 = blo(kvu.w), v3 = bhi(kvu.w);
        a0 = fmaf(f, v0, a0);
        a1 = fmaf(f, v1, a1);
        a2 = fmaf(f, v2, a2);
        a3 = fmaf(f, v3, a3);
    }

#pragma unroll
    for (int mask = 16; mask <= 32; mask <<= 1) {
        lsum += __shfl_xor(lsum, mask);
        Sfa  += __shfl_xor(Sfa,  mask);
        a0   += __shfl_xor(a0,   mask);
        a1   += __shfl_xor(a1,   mask);
        a2   += __shfl_xor(a2,   mask);
        a3   += __shfl_xor(a3,   mask);
    }

    if (quarter == 0) {
        float inv = 1.f / (lsum + 1e-16f);
        uint2 sp = *(const uint2*)(skiparr + (size_t)node * 256 + cb);
        ushort4 o;
        o.x = f2bf(fmaf(we4.x, Sfa, fmaf(be4.x, lsum, a0)) * inv + blo(sp.x));
        o.y = f2bf(fmaf(we4.y, Sfa, fmaf(be4.y, lsum, a1)) * inv + bhi(sp.x));
        o.z = f2bf(fmaf(we4.z, Sfa, fmaf(be4.z, lsum, a2)) * inv + blo(sp.y));
        o.w = f2bf(fmaf(we4.w, Sfa, fmaf(be4.w, lsum, a3)) * inv + bhi(sp.y));
        *(ushort4*)(outb + (size_t)node * 256 + cb) = o;
    }
}

// ---------------------------------------------------------------------------
// GraphNorm column sums (bf16 input).
// ---------------------------------------------------------------------------
__global__ __launch_bounds__(256) void la_colsum(
    const unsigned short* __restrict__ outb, float* __restrict__ cs,
    float* __restrict__ cs2, int n)
{
    const int col = threadIdx.x;
    const int r0 = blockIdx.x * 64;
    const int rend = (r0 + 64 < n) ? r0 + 64 : n;
    float s = 0.f, s2 = 0.f;
    for (int r = r0; r < rend; ++r) {
        float vv = bf2f(outb[(size_t)r * 256 + col]);
        s += vv;
        s2 = fmaf(vv, vv, s2);
    }
    atomicAdd(&cs[col], s);
    atomicAdd(&cs2[col], s2);
}

// ---------------------------------------------------------------------------
// Gram via MFMA (bf16 input, in-block GraphNorm coeffs): xt = R^T R,
// R = relu(out*A + B). Grid = 3*KSPLIT; tile = bx%3: 0=(0,0), 1=(0,128)
// mirrored, 2=(128,128). LDS dword-packed k-pairs, XOR swizzle.
// ---------------------------------------------------------------------------
__global__ __launch_bounds__(256) void la_gram_mfma(
    const unsigned short* __restrict__ outb,
    const float* __restrict__ cs, const float* __restrict__ cs2,
    const float* __restrict__ gnw, const float* __restrict__ gnb,
    const float* __restrict__ gms,
    float* __restrict__ xt, int n, int kchunk)
{
    __shared__ __align__(16) unsigned int Ta[128 * 20];
    __shared__ __align__(16) unsigned int Tb[128 * 20];

    const int bx = blockIdx.x;
    const int kc   = bx / 3;
    const int tile = bx - kc * 3;              // 0,1,2
    const int i0 = (tile == 2) ? 128 : 0;
    const int j0 = (tile == 0) ? 0 : 128;
    const bool diag = (tile != 1);
    const int kbeg = kc * kchunk;
    if (kbeg >= n) return;
    const int kend = (kbeg + kchunk < n) ? kbeg + kchunk : n;

    const int t = threadIdx.x;
    const int l = t & 63, w = t >> 6;
    const int wr = w >> 1, wc = w & 1;
    const int l15 = l & 15, l4 = l >> 4;

    const int kp  = t >> 4;    // 0..15 : k-pair
    const int cg8 = t & 15;    // cols cg8*8 .. +7

    const float invn = 1.f / (float)n;
    float Ai[8], Bi[8], Aj[8], Bj[8];
#pragma unroll
    for (int j = 0; j < 8; ++j) {
        {
            int ci = i0 + cg8 * 8 + j;
            float mean = cs[ci] * invn;
            float m2   = cs2[ci] * invn;
            float s    = gms[ci];
            float var  = m2 - 2.f * s * mean * mean + s * s * mean * mean;
            float a    = gnw[ci] / sqrtf(var + 1e-5f);
            Ai[j] = a; Bi[j] = gnb[ci] - s * mean * a;
        }
        {
            int cj = j0 + cg8 * 8 + j;
            float mean = cs[cj] * invn;
            float m2   = cs2[cj] * invn;
            float s    = gms[cj];
            float var  = m2 - 2.f * s * mean * mean + s * s * mean * mean;
            float a    = gnw[cj] / sqrtf(var + 1e-5f);
            Aj[j] = a; Bj[j] = gnb[cj] - s * mean * a;
        }
    }

    f32x4 acc[4][4];
#pragma unroll
    for (int i = 0; i < 4; ++i)
#pragma unroll
        for (int j = 0; j < 4; ++j) acc[i][j] = (f32x4){0.f, 0.f, 0.f, 0.f};

    const int nsteps = (kend - kbeg + 31) >> 5;
    for (int ks = 0; ks < nsteps; ++ks) {
        const int gr0 = kbeg + ks * 32 + kp * 2;
        const bool v0 = (gr0 < kend), v1 = (gr0 + 1 < kend);

        {
            uint4 u0 = make_uint4(0,0,0,0), u1 = make_uint4(0,0,0,0);
            if (v0) u0 = *(const uint4*)(outb + (size_t)gr0 * 256 + i0 + cg8 * 8);
            if (v1) u1 = *(const uint4*)(outb + (size_t)(gr0+1) * 256 + i0 + cg8 * 8);
            float xs[8] = {blo(u0.x),bhi(u0.x),blo(u0.y),bhi(u0.y),
                           blo(u0.z),bhi(u0.z),blo(u0.w),bhi(u0.w)};
            float ys[8] = {blo(u1.x),bhi(u1.x),blo(u1.y),bhi(u1.y),
                           blo(u1.z),bhi(u1.z),blo(u1.w),bhi(u1.w)};
#pragma unroll
            for (int j = 0; j < 8; ++j) {
                float r0 = v0 ? fmaxf(fmaf(xs[j], Ai[j], Bi[j]), 0.f) : 0.f;
                float r1 = v1 ? fmaxf(fmaf(ys[j], Ai[j], Bi[j]), 0.f) : 0.f;
                int c = cg8 * 8 + j;
                unsigned int u = (unsigned int)f2bf(r0)
                               | ((unsigned int)f2bf(r1) << 16);
                Ta[c * 20 + (kp ^ (((c >> 3) & 3) << 2))] = u;
            }
        }
        if (!diag) {
            uint4 u0 = make_uint4(0,0,0,0), u1 = make_uint4(0,0,0,0);
            if (v0) u0 = *(const uint4*)(outb + (size_t)gr0 * 256 + j0 + cg8 * 8);
            if (v1) u1 = *(const uint4*)(outb + (size_t)(gr0+1) * 256 + j0 + cg8 * 8);
            float xs[8] = {blo(u0.x),bhi(u0.x),blo(u0.y),bhi(u0.y),
                           blo(u0.z),bhi(u0.z),blo(u0.w),bhi(u0.w)};
            float ys[8] = {blo(u1.x),bhi(u1.x),blo(u1.y),bhi(u1.y),
                           blo(u1.z),bhi(u1.z),blo(u1.w),bhi(u1.w)};
#pragma unroll
            for (int j = 0; j < 8; ++j) {
                float r0 = v0 ? fmaxf(fmaf(xs[j], Aj[j], Bj[j]), 0.f) : 0.f;
                float r1 = v1 ? fmaxf(fmaf(ys[j], Aj[j], Bj[j]), 0.f) : 0.f;
                int c = cg8 * 8 + j;
                unsigned int u = (unsigned int)f2bf(r0)
                               | ((unsigned int)f2bf(r1) << 16);
                Tb[c * 20 + (kp ^ (((c >> 3) & 3) << 2))] = u;
            }
        }
        __syncthreads();

        const unsigned int* TB = diag ? Ta : Tb;
        s16x8 af[4], bfr[4];
#pragma unroll
        for (int f = 0; f < 4; ++f) {
            int ca = wr * 64 + f * 16 + l15;
            af[f] = *(const s16x8*)(Ta + ca * 20 + ((l4 * 4) ^ (((ca >> 3) & 3) << 2)));
            int cb2 = wc * 64 + f * 16 + l15;
            bfr[f] = *(const s16x8*)(TB + cb2 * 20 + ((l4 * 4) ^ (((cb2 >> 3) & 3) << 2)));
        }
#pragma unroll
        for (int fm = 0; fm < 4; ++fm)
#pragma unroll
            for (int fn = 0; fn < 4; ++fn)
                acc[fm][fn] = __builtin_amdgcn_mfma_f32_16x16x32_bf16(
                    af[fm], bfr[fn], acc[fm][fn], 0, 0, 0);
        __syncthreads();
    }

#pragma unroll
    for (int fm = 0; fm < 4; ++fm)
#pragma unroll
        for (int fn = 0; fn < 4; ++fn) {
            int col = j0 + wc * 64 + fn * 16 + l15;
#pragma unroll
            for (int j = 0; j < 4; ++j) {
                int row = i0 + wr * 64 + fm * 16 + l4 * 4 + j;
                float vv = acc[fm][fn][j];
                atomicAdd(&xt[(size_t)row * 256 + col], vv);
                if (tile == 1)
                    atomicAdd(&xt[(size_t)col * 256 + row], vv);
            }
        }
}

// ---------------------------------------------------------------------------
// min/max partials (32 blocks), final reduce folded into la_norm prologue.
// ---------------------------------------------------------------------------
__global__ __launch_bounds__(256) void la_minmax_part(
    const float* __restrict__ xt, float* __restrict__ mmp)
{
    const int b = blockIdx.x, t = threadIdx.x;
    float mn = INFINITY, mx = -INFINITY;
#pragma unroll
    for (int k = 0; k < 2; ++k) {
        float4 v = ((const float4*)xt)[b * 512 + k * 256 + t];
        mn = fminf(mn, fminf(fminf(v.x, v.y), fminf(v.z, v.w)));
        mx = fmaxf(mx, fmaxf(fmaxf(v.x, v.y), fmaxf(v.z, v.w)));
    }
#pragma unroll
    for (int mask = 32; mask >= 1; mask >>= 1) {
        mn = fminf(mn, __shfl_xor(mn, mask));
        mx = fmaxf(mx, __shfl_xor(mx, mask));
    }
    __shared__ float smn[4], smx[4];
    if ((t & 63) == 0) { smn[t >> 6] = mn; smx[t >> 6] = mx; }
    __syncthreads();
    if (t == 0) {
        mn = fminf(fminf(smn[0], smn[1]), fminf(smn[2], smn[3]));
        mx = fmaxf(fmaxf(smx[0], smx[1]), fmaxf(smx[2], smx[3]));
        mmp[b * 2]     = mn;
        mmp[b * 2 + 1] = mx;
    }
}

__global__ void la_norm(float* __restrict__ xt, const float* __restrict__ mmp)
{
    float mn = INFINITY, mx = -INFINITY;
#pragma unroll
    for (int i = 0; i < 32; ++i) {
        mn = fminf(mn, mmp[i * 2]);
        mx = fmaxf(mx, mmp[i * 2 + 1]);
    }
    float inv = 1.f / (mx - mn + 1e-8f);
    int i = blockIdx.x * blockDim.x + threadIdx.x;
    xt[i] = (xt[i] - mn) * inv;
}

// ---------------------------------------------------------------------------
extern "C" void kernel_launch(void* const* d_in, const int* in_sizes, int n_in,
                              void* d_out, int out_size, void* d_ws, size_t ws_size,
                              hipStream_t stream)
{
    const float* x   = (const float*)d_in[0];
    const int*   ei  = (const int*)  d_in[1];
    const float* ea  = (const float*)d_in[2];
    const float* Wq  = (const float*)d_in[3];
    const float* bq  = (const float*)d_in[4];
    const float* Wk  = (const float*)d_in[5];
    const float* bk  = (const float*)d_in[6];
    const float* Wv  = (const float*)d_in[7];
    const float* bv  = (const float*)d_in[8];
    const float* We  = (const float*)d_in[9];
    const float* be  = (const float*)d_in[10];
    const float* Ws  = (const float*)d_in[11];
    const float* bs  = (const float*)d_in[12];
    const float* gnw = (const float*)d_in[13];
    const float* gnb = (const float*)d_in[14];
    const float* gms = (const float*)d_in[15];

    const int n = in_sizes[0] / 256;
    const int e = in_sizes[1] / 2;
    const int* srcI = ei;
    const int* dstI = ei + e;

    char* ws = (char*)d_ws;
    size_t off = 0;
    auto take = [&](size_t bytes) -> void* {
        void* p = (void*)(ws + off);
        off += (bytes + 255) & ~(size_t)255;
        return p;
    };
    unsigned short* xb    = (unsigned short*)take((size_t)n * 256 * 2);
    unsigned short* wtbuf = (unsigned short*)take((size_t)1024 * 256 * 2);
    float*          bcat  = (float*)take(1024 * 4);
    unsigned short* qarr  = (unsigned short*)take((size_t)n * 256 * 2);
    unsigned short* kv    = (unsigned short*)take((size_t)n * 512 * 2);
    unsigned short* skipb = (unsigned short*)take((size_t)n * 256 * 2);
    unsigned short* outb  = (unsigned short*)take((size_t)n * 256 * 2);
    int*   deg    = (int*)  take((size_t)n * 4);
    int*   cursor = (int*)  take((size_t)n * 4);
    int*   offs   = (int*)  take((size_t)(n + 1) * 4);
    int*   part   = (int*)  take(256 * 4);
    uint2* csrR   = (uint2*)take((size_t)e * 8);
    float* cs     = (float*)take(256 * 4);
    float* cs2    = (float*)take(256 * 4);
    float* mmp    = (float*)take(64 * 4);
    (void)ws_size; (void)n_in; (void)out_size;

    float* xt = (float*)d_out;

    hipMemsetAsync(deg, 0, (size_t)n * 4, stream);
    hipMemsetAsync(cs,  0, 256 * 4, stream);
    hipMemsetAsync(cs2, 0, 256 * 4, stream);
    hipMemsetAsync(xt,  0, (size_t)65536 * 4, stream);

    la_x2bf  <<<2048, 256, 0, stream>>>(x, xb, n * 64);
    la_wprep2<<<64, 256, 0, stream>>>(Wq, Wk, Wv, Ws, bq, bk, bv, bs, wtbuf, bcat);

    dim3 gg((n + 127) / 128, 8);
    la_gemm_mfma<<<gg, 256, 0, stream>>>(xb, wtbuf, bcat, qarr, kv, skipb, n);

    const int nchunk = (n + 255) / 256;
    la_hist     <<<1024, 256, 0, stream>>>(dstI, e, deg);
    la_chunksum <<<nchunk, 256, 0, stream>>>(deg, n, part);
    la_scanpart <<<1, 256, 0, stream>>>(part, nchunk);
    la_scanfinal<<<nchunk, 256, 0, stream>>>(deg, n, part, offs, cursor, e);
    la_scatter  <<<1024, 256, 0, stream>>>(srcI, dstI, ea, e, cursor, csrR);

    la_attn3<<<n, 256, 0, stream>>>(qarr, kv, skipb, csrR, offs, We, be, outb);

    la_colsum<<<(n + 63) / 64, 256, 0, stream>>>(outb, cs, cs2, n);

    const int KSPLIT = 64;
    int kchunk = ((n + KSPLIT - 1) / KSPLIT + 31) & ~31;
    la_gram_mfma<<<3 * KSPLIT, 256, 0, stream>>>(outb, cs, cs2, gnw, gnb, gms,
                                                 xt, n, kchunk);

    la_minmax_part<<<32, 256, 0, stream>>>(xt, mmp);
    la_norm<<<256, 256, 0, stream>>>(xt, mmp);
}

// Round 9
// 410.804 us; speedup vs baseline: 1.1978x; 1.1210x over previous
//
#include <hip/hip_runtime.h>
#include <math.h>

// F_IN = HC = 256, H = 4, C = 64. N, E from in_sizes.

typedef float f32x4 __attribute__((ext_vector_type(4)));
typedef short s16x8 __attribute__((ext_vector_type(8)));

static __device__ __forceinline__ unsigned short f2bf(float f) {
    unsigned int u = __float_as_uint(f);
    unsigned int r = u + 0x7FFFu + ((u >> 16) & 1u);   // RNE
    return (unsigned short)(r >> 16);
}
static __device__ __forceinline__ float bf2f(unsigned short u) {
    return __uint_as_float(((unsigned int)u) << 16);
}
static __device__ __forceinline__ float blo(unsigned int u) {
    return __uint_as_float(u << 16);
}
static __device__ __forceinline__ float bhi(unsigned int u) {
    return __uint_as_float(u & 0xffff0000u);
}

#define LOG2E_8 0.18033688011112042f   // log2(e)/8

// ---------------------------------------------------------------------------
// Fused prep: blocks [0,64) W transpose, [64,1088) hist(+pos), [1088,3136) x2bf
// ---------------------------------------------------------------------------
__global__ __launch_bounds__(256) void la_prep(
    const float* __restrict__ x, int total4,
    const float* __restrict__ Wq, const float* __restrict__ Wk,
    const float* __restrict__ Wv, const float* __restrict__ Ws,
    const float* __restrict__ bq, const float* __restrict__ bk,
    const float* __restrict__ bv, const float* __restrict__ bs,
    unsigned short* __restrict__ wt, float* __restrict__ bcat,
    const int* __restrict__ dst, int e,
    int* __restrict__ deg, int* __restrict__ pos,
    unsigned short* __restrict__ xb)
{
    __shared__ float T[64][68];
    const int bid = blockIdx.x;
    const int t = threadIdx.x;

    if (bid < 64) {
        // ---- W transpose tile ----
        const int m  = bid >> 4;
        const int kt = (bid >> 2) & 3, ct = bid & 3;
        const int k0 = kt * 64, c0 = ct * 64;
        const float* W = (m == 0) ? Wq : (m == 1) ? Wk : (m == 2) ? Wv : Ws;
        const float* B = (m == 0) ? bq : (m == 1) ? bk : (m == 2) ? bv : bs;
#pragma unroll
        for (int it = 0; it < 4; ++it) {
            int s = it * 256 + t;
            int r = s >> 4;
            int q = (s & 15) * 4;
            float4 v = *(const float4*)(W + (size_t)(k0 + r) * 256 + c0 + q);
            T[r][q + 0] = v.x; T[r][q + 1] = v.y;
            T[r][q + 2] = v.z; T[r][q + 3] = v.w;
        }
        __syncthreads();
#pragma unroll
        for (int it = 0; it < 4; ++it) {
            int s = it * 256 + t;
            int c = s >> 4;
            int kq = (s & 15) * 4;
            ushort4 o;
            o.x = f2bf(T[kq + 0][c]); o.y = f2bf(T[kq + 1][c]);
            o.z = f2bf(T[kq + 2][c]); o.w = f2bf(T[kq + 3][c]);
            *(ushort4*)(wt + (size_t)(m * 256 + c0 + c) * 256 + k0 + kq) = o;
        }
        if (kt == 0 && t < 64) bcat[m * 256 + c0 + t] = B[c0 + t];
    } else if (bid < 1088) {
        // ---- histogram + per-edge rank ----
        int i = (bid - 64) * 256 + t;
        const int stride = 1024 * 256;
        for (; i < e; i += stride)
            pos[i] = atomicAdd(&deg[dst[i]], 1);
    } else {
        // ---- x fp32 -> bf16 ----
        int i = (bid - 1088) * 256 + t;
        const int stride = 2048 * 256;
        for (; i < total4; i += stride) {
            float4 v = ((const float4*)x)[i];
            ushort4 o;
            o.x = f2bf(v.x); o.y = f2bf(v.y); o.z = f2bf(v.z); o.w = f2bf(v.w);
            ((ushort4*)xb)[i] = o;
        }
    }
}

// ---------------------------------------------------------------------------
// MFMA GEMM: 128x128 tile, 4 waves each 64x64 (4x4 frags). Grid (n/128, 8).
// Outputs: msel 0 qarr, 1/2 kv packed, 3 skip.
// ---------------------------------------------------------------------------
__global__ __launch_bounds__(256) void la_gemm_mfma(
    const unsigned short* __restrict__ xb, const unsigned short* __restrict__ wt,
    const float* __restrict__ bcat,
    unsigned short* __restrict__ qarr, unsigned short* __restrict__ kv,
    unsigned short* __restrict__ skiparr, int n)
{
    __shared__ __align__(16) unsigned short As[128 * 40];
    __shared__ __align__(16) unsigned short Bs[128 * 40];

    const int row0 = blockIdx.x * 128;
    const int col0 = blockIdx.y * 128;
    const int msel = blockIdx.y >> 1;
    const int t = threadIdx.x;
    const int l = t & 63;
    const int w = t >> 6;
    const int wr = w >> 1, wc = w & 1;
    const int l15 = l & 15, l4 = l >> 4;

    f32x4 acc[4][4];
#pragma unroll
    for (int i = 0; i < 4; ++i)
#pragma unroll
        for (int j = 0; j < 4; ++j) acc[i][j] = (f32x4){0.f, 0.f, 0.f, 0.f};

    for (int k0 = 0; k0 < 256; k0 += 32) {
#pragma unroll
        for (int c2 = 0; c2 < 2; ++c2) {
            int chunk = t + c2 * 256;
            int r  = chunk >> 2;
            int ko = (chunk & 3) * 8;
            int ga = row0 + r;
            s16x8 va = (s16x8){0,0,0,0,0,0,0,0};
            if (ga < n) va = *(const s16x8*)(xb + (size_t)ga * 256 + k0 + ko);
            *(s16x8*)(As + r * 40 + ko) = va;
            int gb = col0 + r;
            s16x8 vb = *(const s16x8*)(wt + (size_t)gb * 256 + k0 + ko);
            *(s16x8*)(Bs + r * 40 + ko) = vb;
        }
        __syncthreads();
        s16x8 af[4], bfr[4];
#pragma unroll
        for (int f = 0; f < 4; ++f) {
            af[f]  = *(const s16x8*)(As + (wr * 64 + f * 16 + l15) * 40 + l4 * 8);
            bfr[f] = *(const s16x8*)(Bs + (wc * 64 + f * 16 + l15) * 40 + l4 * 8);
        }
#pragma unroll
        for (int fm = 0; fm < 4; ++fm)
#pragma unroll
            for (int fn = 0; fn < 4; ++fn)
                acc[fm][fn] = __builtin_amdgcn_mfma_f32_16x16x32_bf16(
                    af[fm], bfr[fn], acc[fm][fn], 0, 0, 0);
        __syncthreads();
    }

#pragma unroll
    for (int fm = 0; fm < 4; ++fm) {
#pragma unroll
        for (int fn = 0; fn < 4; ++fn) {
            int gc = col0 + wc * 64 + fn * 16 + l15;
            int c  = gc & 255;
            float bb = bcat[gc];
#pragma unroll
            for (int j = 0; j < 4; ++j) {
                int gr = row0 + wr * 64 + fm * 16 + l4 * 4 + j;
                if (gr >= n) continue;
                unsigned short val = f2bf(acc[fm][fn][j] + bb);
                if (msel == 0) {
                    qarr[(size_t)gr * 256 + c] = val;
                } else if (msel == 3) {
                    skiparr[(size_t)gr * 256 + c] = val;
                } else {
                    int hh = c >> 6, ch = c & 63;
                    size_t idx = (size_t)gr * 512 + hh * 128 + (ch >> 2) * 8
                               + (ch & 3) + ((msel == 2) ? 4 : 0);
                    kv[idx] = val;
                }
            }
        }
    }
}

// ---------------------------------------------------------------------------
// Scan: chunk sums -> 1-block exclusive scan of partials -> final offsets.
// ---------------------------------------------------------------------------
__global__ void la_chunksum(const int* __restrict__ deg, int n, int* __restrict__ part)
{
    int b = blockIdx.x, t = threadIdx.x;
    int i = b * 256 + t;
    int v = (i < n) ? deg[i] : 0;
#pragma unroll
    for (int mask = 32; mask >= 1; mask >>= 1) v += __shfl_xor(v, mask);
    __shared__ int ws[4];
    if ((t & 63) == 0) ws[t >> 6] = v;
    __syncthreads();
    if (t == 0) part[b] = ws[0] + ws[1] + ws[2] + ws[3];
}

__global__ void la_scanpart(int* __restrict__ part, int nb)   // nb <= 256
{
    __shared__ int s[256];
    int t = threadIdx.x;
    int v = (t < nb) ? part[t] : 0;
    int orig = v;
    s[t] = v;
    __syncthreads();
    for (int o = 1; o < 256; o <<= 1) {
        int u = (t >= o) ? s[t - o] : 0;
        __syncthreads();
        s[t] += u;
        __syncthreads();
    }
    if (t < nb) part[t] = s[t] - orig;   // exclusive
}

__global__ void la_scanfinal(const int* __restrict__ deg, int n,
                             const int* __restrict__ part, int* __restrict__ offs,
                             int e)
{
    int b = blockIdx.x, t = threadIdx.x;
    int i = b * 256 + t;
    int d = (i < n) ? deg[i] : 0;
    int v = d;
#pragma unroll
    for (int o = 1; o < 64; o <<= 1) {
        int u = __shfl_up(v, o);
        if ((t & 63) >= o) v += u;
    }
    __shared__ int wt[4];
    if ((t & 63) == 63) wt[t >> 6] = v;
    __syncthreads();
    int add = 0;
    for (int wv = 0; wv < (t >> 6); ++wv) add += wt[wv];
    int excl = v + add - d + part[b];
    if (i < n) offs[i] = excl;
    if (b == 0 && t == 0) offs[n] = e;
}

// ---------------------------------------------------------------------------
// Scatter, atomic-free: final slot = offs[dst] + pos (rank from la_prep).
// ---------------------------------------------------------------------------
__global__ void la_scatter2(const int* __restrict__ src, const int* __restrict__ dst,
                            const float* __restrict__ ea,
                            const int* __restrict__ pos,
                            const int* __restrict__ offs, int e,
                            uint2* __restrict__ rec)
{
    int i = blockIdx.x * blockDim.x + threadIdx.x;
    int stride = gridDim.x * blockDim.x;
    for (; i < e; i += stride) {
        int d = dst[i];
        int p = offs[d] + pos[i];
        rec[p] = make_uint2((unsigned int)src[i], __float_as_uint(ea[i]));
    }
}

// ---------------------------------------------------------------------------
// Attention v3: block = node, wave = head. 4 edges/wave-iter (16-lane
// quarters), 4 channels/lane, one dwordx4 kv gather per lane per edge.
// Writes outb as bf16.
// ---------------------------------------------------------------------------
__global__ __launch_bounds__(256) void la_attn3(
    const unsigned short* __restrict__ qarr,
    const unsigned short* __restrict__ kv,
    const unsigned short* __restrict__ skiparr,
    const uint2* __restrict__ rec,
    const int* __restrict__ offs,
    const float* __restrict__ We, const float* __restrict__ be,
    unsigned short* __restrict__ outb)
{
    const int node = blockIdx.x;
    const int t = threadIdx.x;
    const int h = t >> 6;
    const int l = t & 63;
    const int quarter = l >> 4;
    const int lc = l & 15;
    const int cb = h * 64 + lc * 4;     // channel base (4 per lane)

    uint2 qp = *(const uint2*)(qarr + (size_t)node * 256 + cb);
    const float q0 = blo(qp.x), q1 = bhi(qp.x);
    const float q2 = blo(qp.y), q3 = bhi(qp.y);
    float4 we4 = *(const float4*)(We + cb);
    float4 be4 = *(const float4*)(be + cb);

    float pw = fmaf(q3, we4.w, fmaf(q2, we4.z, fmaf(q1, we4.y, q0 * we4.x)));
    float pb = fmaf(q3, be4.w, fmaf(q2, be4.z, fmaf(q1, be4.y, q0 * be4.x)));
#pragma unroll
    for (int mask = 1; mask <= 8; mask <<= 1) {
        pw += __shfl_xor(pw, mask);
        pb += __shfl_xor(pb, mask);
    }
    const float qWe8 = pw * LOG2E_8;
    const float qbe8 = pb * LOG2E_8;

    const int start = offs[node], end = offs[node + 1];
    const int koff = h * 128 + lc * 8;

    float lsum = 0.f, Sfa = 0.f;
    float a0 = 0.f, a1 = 0.f, a2 = 0.f, a3 = 0.f;

    for (int j0 = start; j0 < end; j0 += 4) {
        int j = j0 + quarter;
        bool valid = (j < end);
        int jj = valid ? j : j0;
        uint2 r = rec[jj];
        int   s   = (int)r.x;
        float eaj = __uint_as_float(r.y);
        uint4 kvu = *(const uint4*)(kv + (((size_t)s) << 9) + koff);
        float k0 = blo(kvu.x), k1 = bhi(kvu.x);
        float k2 = blo(kvu.y), k3 = bhi(kvu.y);
        float d = fmaf(q3, k3, fmaf(q2, k2, fmaf(q1, k1, q0 * k0)));
#pragma unroll
        for (int mask = 1; mask <= 8; mask <<= 1) d += __shfl_xor(d, mask);
        float aL = fmaf(d, LOG2E_8, fmaf(eaj, qWe8, qbe8));
        aL = valid ? aL : -INFINITY;
        float f = exp2f(aL);
        lsum += f;
        Sfa = fmaf(f, eaj, Sfa);
        float v0 = blo(kvu.z), v1 = bhi(kvu.z);
        float v2 = blo(kvu.w), v3 = bhi(kvu.w);
        a0 = fmaf(f, v0, a0);
        a1 = fmaf(f, v1, a1);
        a2 = fmaf(f, v2, a2);
        a3 = fmaf(f, v3, a3);
    }

#pragma unroll
    for (int mask = 16; mask <= 32; mask <<= 1) {
        lsum += __shfl_xor(lsum, mask);
        Sfa  += __shfl_xor(Sfa,  mask);
        a0   += __shfl_xor(a0,   mask);
        a1   += __shfl_xor(a1,   mask);
        a2   += __shfl_xor(a2,   mask);
        a3   += __shfl_xor(a3,   mask);
    }

    if (quarter == 0) {
        float inv = 1.f / (lsum + 1e-16f);
        uint2 sp = *(const uint2*)(skiparr + (size_t)node * 256 + cb);
        ushort4 o;
        o.x = f2bf(fmaf(we4.x, Sfa, fmaf(be4.x, lsum, a0)) * inv + blo(sp.x));
        o.y = f2bf(fmaf(we4.y, Sfa, fmaf(be4.y, lsum, a1)) * inv + bhi(sp.x));
        o.z = f2bf(fmaf(we4.z, Sfa, fmaf(be4.z, lsum, a2)) * inv + blo(sp.y));
        o.w = f2bf(fmaf(we4.w, Sfa, fmaf(be4.w, lsum, a3)) * inv + bhi(sp.y));
        *(ushort4*)(outb + (size_t)node * 256 + cb) = o;
    }
}

// ---------------------------------------------------------------------------
// GraphNorm column sums (bf16 input).
// ---------------------------------------------------------------------------
__global__ __launch_bounds__(256) void la_colsum(
    const unsigned short* __restrict__ outb, float* __restrict__ cs,
    float* __restrict__ cs2, int n)
{
    const int col = threadIdx.x;
    const int r0 = blockIdx.x * 64;
    const int rend = (r0 + 64 < n) ? r0 + 64 : n;
    float s = 0.f, s2 = 0.f;
    for (int r = r0; r < rend; ++r) {
        float vv = bf2f(outb[(size_t)r * 256 + col]);
        s += vv;
        s2 = fmaf(vv, vv, s2);
    }
    atomicAdd(&cs[col], s);
    atomicAdd(&cs2[col], s2);
}

// ---------------------------------------------------------------------------
// Gram via MFMA (bf16 input, in-block GraphNorm coeffs): xt = R^T R,
// R = relu(out*A + B). Grid = 3*KSPLIT; tile = bx%3: 0=(0,0), 1=(0,128)
// mirrored, 2=(128,128). LDS dword-packed k-pairs, XOR swizzle.
// ---------------------------------------------------------------------------
__global__ __launch_bounds__(256) void la_gram_mfma(
    const unsigned short* __restrict__ outb,
    const float* __restrict__ cs, const float* __restrict__ cs2,
    const float* __restrict__ gnw, const float* __restrict__ gnb,
    const float* __restrict__ gms,
    float* __restrict__ xt, int n, int kchunk)
{
    __shared__ __align__(16) unsigned int Ta[128 * 20];
    __shared__ __align__(16) unsigned int Tb[128 * 20];

    const int bx = blockIdx.x;
    const int kc   = bx / 3;
    const int tile = bx - kc * 3;              // 0,1,2
    const int i0 = (tile == 2) ? 128 : 0;
    const int j0 = (tile == 0) ? 0 : 128;
    const bool diag = (tile != 1);
    const int kbeg = kc * kchunk;
    if (kbeg >= n) return;
    const int kend = (kbeg + kchunk < n) ? kbeg + kchunk : n;

    const int t = threadIdx.x;
    const int l = t & 63, w = t >> 6;
    const int wr = w >> 1, wc = w & 1;
    const int l15 = l & 15, l4 = l >> 4;

    const int kp  = t >> 4;    // 0..15 : k-pair
    const int cg8 = t & 15;    // cols cg8*8 .. +7

    const float invn = 1.f / (float)n;
    float Ai[8], Bi[8], Aj[8], Bj[8];
#pragma unroll
    for (int j = 0; j < 8; ++j) {
        {
            int ci = i0 + cg8 * 8 + j;
            float mean = cs[ci] * invn;
            float m2   = cs2[ci] * invn;
            float s    = gms[ci];
            float var  = m2 - 2.f * s * mean * mean + s * s * mean * mean;
            float a    = gnw[ci] / sqrtf(var + 1e-5f);
            Ai[j] = a; Bi[j] = gnb[ci] - s * mean * a;
        }
        {
            int cj = j0 + cg8 * 8 + j;
            float mean = cs[cj] * invn;
            float m2   = cs2[cj] * invn;
            float s    = gms[cj];
            float var  = m2 - 2.f * s * mean * mean + s * s * mean * mean;
            float a    = gnw[cj] / sqrtf(var + 1e-5f);
            Aj[j] = a; Bj[j] = gnb[cj] - s * mean * a;
        }
    }

    f32x4 acc[4][4];
#pragma unroll
    for (int i = 0; i < 4; ++i)
#pragma unroll
        for (int j = 0; j < 4; ++j) acc[i][j] = (f32x4){0.f, 0.f, 0.f, 0.f};

    const int nsteps = (kend - kbeg + 31) >> 5;
    for (int ks = 0; ks < nsteps; ++ks) {
        const int gr0 = kbeg + ks * 32 + kp * 2;
        const bool v0 = (gr0 < kend), v1 = (gr0 + 1 < kend);

        {
            uint4 u0 = make_uint4(0,0,0,0), u1 = make_uint4(0,0,0,0);
            if (v0) u0 = *(const uint4*)(outb + (size_t)gr0 * 256 + i0 + cg8 * 8);
            if (v1) u1 = *(const uint4*)(outb + (size_t)(gr0+1) * 256 + i0 + cg8 * 8);
            float xs[8] = {blo(u0.x),bhi(u0.x),blo(u0.y),bhi(u0.y),
                           blo(u0.z),bhi(u0.z),blo(u0.w),bhi(u0.w)};
            float ys[8] = {blo(u1.x),bhi(u1.x),blo(u1.y),bhi(u1.y),
                           blo(u1.z),bhi(u1.z),blo(u1.w),bhi(u1.w)};
#pragma unroll
            for (int j = 0; j < 8; ++j) {
                float r0 = v0 ? fmaxf(fmaf(xs[j], Ai[j], Bi[j]), 0.f) : 0.f;
                float r1 = v1 ? fmaxf(fmaf(ys[j], Ai[j], Bi[j]), 0.f) : 0.f;
                int c = cg8 * 8 + j;
                unsigned int u = (unsigned int)f2bf(r0)
                               | ((unsigned int)f2bf(r1) << 16);
                Ta[c * 20 + (kp ^ (((c >> 3) & 3) << 2))] = u;
            }
        }
        if (!diag) {
            uint4 u0 = make_uint4(0,0,0,0), u1 = make_uint4(0,0,0,0);
            if (v0) u0 = *(const uint4*)(outb + (size_t)gr0 * 256 + j0 + cg8 * 8);
            if (v1) u1 = *(const uint4*)(outb + (size_t)(gr0+1) * 256 + j0 + cg8 * 8);
            float xs[8] = {blo(u0.x),bhi(u0.x),blo(u0.y),bhi(u0.y),
                           blo(u0.z),bhi(u0.z),blo(u0.w),bhi(u0.w)};
            float ys[8] = {blo(u1.x),bhi(u1.x),blo(u1.y),bhi(u1.y),
                           blo(u1.z),bhi(u1.z),blo(u1.w),bhi(u1.w)};
#pragma unroll
            for (int j = 0; j < 8; ++j) {
                float r0 = v0 ? fmaxf(fmaf(xs[j], Aj[j], Bj[j]), 0.f) : 0.f;
                float r1 = v1 ? fmaxf(fmaf(ys[j], Aj[j], Bj[j]), 0.f) : 0.f;
                int c = cg8 * 8 + j;
                unsigned int u = (unsigned int)f2bf(r0)
                               | ((unsigned int)f2bf(r1) << 16);
                Tb[c * 20 + (kp ^ (((c >> 3) & 3) << 2))] = u;
            }
        }
        __syncthreads();

        const unsigned int* TB = diag ? Ta : Tb;
        s16x8 af[4], bfr[4];
#pragma unroll
        for (int f = 0; f < 4; ++f) {
            int ca = wr * 64 + f * 16 + l15;
            af[f] = *(const s16x8*)(Ta + ca * 20 + ((l4 * 4) ^ (((ca >> 3) & 3) << 2)));
            int cb2 = wc * 64 + f * 16 + l15;
            bfr[f] = *(const s16x8*)(TB + cb2 * 20 + ((l4 * 4) ^ (((cb2 >> 3) & 3) << 2)));
        }
#pragma unroll
        for (int fm = 0; fm < 4; ++fm)
#pragma unroll
            for (int fn = 0; fn < 4; ++fn)
                acc[fm][fn] = __builtin_amdgcn_mfma_f32_16x16x32_bf16(
                    af[fm], bfr[fn], acc[fm][fn], 0, 0, 0);
        __syncthreads();
    }

#pragma unroll
    for (int fm = 0; fm < 4; ++fm)
#pragma unroll
        for (int fn = 0; fn < 4; ++fn) {
            int col = j0 + wc * 64 + fn * 16 + l15;
#pragma unroll
            for (int j = 0; j < 4; ++j) {
                int row = i0 + wr * 64 + fm * 16 + l4 * 4 + j;
                float vv = acc[fm][fn][j];
                atomicAdd(&xt[(size_t)row * 256 + col], vv);
                if (tile == 1)
                    atomicAdd(&xt[(size_t)col * 256 + row], vv);
            }
        }
}

// ---------------------------------------------------------------------------
// min/max partials (32 blocks), final reduce folded into la_norm prologue.
// ---------------------------------------------------------------------------
__global__ __launch_bounds__(256) void la_minmax_part(
    const float* __restrict__ xt, float* __restrict__ mmp)
{
    const int b = blockIdx.x, t = threadIdx.x;
    float mn = INFINITY, mx = -INFINITY;
#pragma unroll
    for (int k = 0; k < 2; ++k) {
        float4 v = ((const float4*)xt)[b * 512 + k * 256 + t];
        mn = fminf(mn, fminf(fminf(v.x, v.y), fminf(v.z, v.w)));
        mx = fmaxf(mx, fmaxf(fmaxf(v.x, v.y), fmaxf(v.z, v.w)));
    }
#pragma unroll
    for (int mask = 32; mask >= 1; mask >>= 1) {
        mn = fminf(mn, __shfl_xor(mn, mask));
        mx = fmaxf(mx, __shfl_xor(mx, mask));
    }
    __shared__ float smn[4], smx[4];
    if ((t & 63) == 0) { smn[t >> 6] = mn; smx[t >> 6] = mx; }
    __syncthreads();
    if (t == 0) {
        mn = fminf(fminf(smn[0], smn[1]), fminf(smn[2], smn[3]));
        mx = fmaxf(fmaxf(smx[0], smx[1]), fmaxf(smx[2], smx[3]));
        mmp[b * 2]     = mn;
        mmp[b * 2 + 1] = mx;
    }
}

__global__ void la_norm(float* __restrict__ xt, const float* __restrict__ mmp)
{
    float mn = INFINITY, mx = -INFINITY;
#pragma unroll
    for (int i = 0; i < 32; ++i) {
        mn = fminf(mn, mmp[i * 2]);
        mx = fmaxf(mx, mmp[i * 2 + 1]);
    }
    float inv = 1.f / (mx - mn + 1e-8f);
    int i = blockIdx.x * blockDim.x + threadIdx.x;
    xt[i] = (xt[i] - mn) * inv;
}

// ---------------------------------------------------------------------------
extern "C" void kernel_launch(void* const* d_in, const int* in_sizes, int n_in,
                              void* d_out, int out_size, void* d_ws, size_t ws_size,
                              hipStream_t stream)
{
    const float* x   = (const float*)d_in[0];
    const int*   ei  = (const int*)  d_in[1];
    const float* ea  = (const float*)d_in[2];
    const float* Wq  = (const float*)d_in[3];
    const float* bq  = (const float*)d_in[4];
    const float* Wk  = (const float*)d_in[5];
    const float* bk  = (const float*)d_in[6];
    const float* Wv  = (const float*)d_in[7];
    const float* bv  = (const float*)d_in[8];
    const float* We  = (const float*)d_in[9];
    const float* be  = (const float*)d_in[10];
    const float* Ws  = (const float*)d_in[11];
    const float* bs  = (const float*)d_in[12];
    const float* gnw = (const float*)d_in[13];
    const float* gnb = (const float*)d_in[14];
    const float* gms = (const float*)d_in[15];

    const int n = in_sizes[0] / 256;
    const int e = in_sizes[1] / 2;
    const int* srcI = ei;
    const int* dstI = ei + e;

    char* ws = (char*)d_ws;
    size_t off = 0;
    auto take = [&](size_t bytes) -> void* {
        void* p = (void*)(ws + off);
        off += (bytes + 255) & ~(size_t)255;
        return p;
    };
    // zero-region: deg | cs | cs2 contiguous -> ONE memset
    int*   deg    = (int*)  take((size_t)n * 4);
    float* cs     = (float*)take(256 * 4);
    float* cs2    = (float*)take(256 * 4);
    size_t zero_bytes = off;   // everything allocated so far gets zeroed

    unsigned short* xb    = (unsigned short*)take((size_t)n * 256 * 2);
    unsigned short* wtbuf = (unsigned short*)take((size_t)1024 * 256 * 2);
    float*          bcat  = (float*)take(1024 * 4);
    unsigned short* qarr  = (unsigned short*)take((size_t)n * 256 * 2);
    unsigned short* kv    = (unsigned short*)take((size_t)n * 512 * 2);
    unsigned short* skipb = (unsigned short*)take((size_t)n * 256 * 2);
    unsigned short* outb  = (unsigned short*)take((size_t)n * 256 * 2);
    int*   pos    = (int*)  take((size_t)e * 4);
    int*   offs   = (int*)  take((size_t)(n + 1) * 4);
    int*   part   = (int*)  take(256 * 4);
    uint2* csrR   = (uint2*)take((size_t)e * 8);
    float* mmp    = (float*)take(64 * 4);
    (void)ws_size; (void)n_in; (void)out_size;

    float* xt = (float*)d_out;

    hipMemsetAsync(deg, 0, zero_bytes, stream);
    hipMemsetAsync(xt,  0, (size_t)65536 * 4, stream);

    la_prep<<<3136, 256, 0, stream>>>(x, n * 64,
                                      Wq, Wk, Wv, Ws, bq, bk, bv, bs,
                                      wtbuf, bcat, dstI, e, deg, pos, xb);

    dim3 gg((n + 127) / 128, 8);
    la_gemm_mfma<<<gg, 256, 0, stream>>>(xb, wtbuf, bcat, qarr, kv, skipb, n);

    const int nchunk = (n + 255) / 256;
    la_chunksum <<<nchunk, 256, 0, stream>>>(deg, n, part);
    la_scanpart <<<1, 256, 0, stream>>>(part, nchunk);
    la_scanfinal<<<nchunk, 256, 0, stream>>>(deg, n, part, offs, e);
    la_scatter2 <<<1024, 256, 0, stream>>>(srcI, dstI, ea, pos, offs, e, csrR);

    la_attn3<<<n, 256, 0, stream>>>(qarr, kv, skipb, csrR, offs, We, be, outb);

    la_colsum<<<(n + 63) / 64, 256, 0, stream>>>(outb, cs, cs2, n);

    const int KSPLIT = 128;
    int kchunk = ((n + KSPLIT - 1) / KSPLIT + 31) & ~31;
    la_gram_mfma<<<3 * KSPLIT, 256, 0, stream>>>(outb, cs, cs2, gnw, gnb, gms,
                                                 xt, n, kchunk);

    la_minmax_part<<<32, 256, 0, stream>>>(xt, mmp);
    la_norm<<<256, 256, 0, stream>>>(xt, mmp);
}

// Round 10
// 386.066 us; speedup vs baseline: 1.2746x; 1.0641x over previous
//
#include <hip/hip_runtime.h>
#include <math.h>

// F_IN = HC = 256, H = 4, C = 64. N, E from in_sizes.

typedef float f32x4 __attribute__((ext_vector_type(4)));
typedef short s16x8 __attribute__((ext_vector_type(8)));

static __device__ __forceinline__ unsigned short f2bf(float f) {
    unsigned int u = __float_as_uint(f);
    unsigned int r = u + 0x7FFFu + ((u >> 16) & 1u);   // RNE
    return (unsigned short)(r >> 16);
}
static __device__ __forceinline__ float bf2f(unsigned short u) {
    return __uint_as_float(((unsigned int)u) << 16);
}
static __device__ __forceinline__ float blo(unsigned int u) {
    return __uint_as_float(u << 16);
}
static __device__ __forceinline__ float bhi(unsigned int u) {
    return __uint_as_float(u & 0xffff0000u);
}

#define LOG2E_8 0.18033688011112042f   // log2(e)/8

// ---------------------------------------------------------------------------
// Fused prep: blocks [0,64) W transpose, [64,1088) hist(+pos), [1088,3136) x2bf
// ---------------------------------------------------------------------------
__global__ __launch_bounds__(256) void la_prep(
    const float* __restrict__ x, int total4,
    const float* __restrict__ Wq, const float* __restrict__ Wk,
    const float* __restrict__ Wv, const float* __restrict__ Ws,
    const float* __restrict__ bq, const float* __restrict__ bk,
    const float* __restrict__ bv, const float* __restrict__ bs,
    unsigned short* __restrict__ wt, float* __restrict__ bcat,
    const int* __restrict__ dst, int e,
    int* __restrict__ deg, int* __restrict__ pos,
    unsigned short* __restrict__ xb)
{
    __shared__ float T[64][68];
    const int bid = blockIdx.x;
    const int t = threadIdx.x;

    if (bid < 64) {
        const int m  = bid >> 4;
        const int kt = (bid >> 2) & 3, ct = bid & 3;
        const int k0 = kt * 64, c0 = ct * 64;
        const float* W = (m == 0) ? Wq : (m == 1) ? Wk : (m == 2) ? Wv : Ws;
        const float* B = (m == 0) ? bq : (m == 1) ? bk : (m == 2) ? bv : bs;
#pragma unroll
        for (int it = 0; it < 4; ++it) {
            int s = it * 256 + t;
            int r = s >> 4;
            int q = (s & 15) * 4;
            float4 v = *(const float4*)(W + (size_t)(k0 + r) * 256 + c0 + q);
            T[r][q + 0] = v.x; T[r][q + 1] = v.y;
            T[r][q + 2] = v.z; T[r][q + 3] = v.w;
        }
        __syncthreads();
#pragma unroll
        for (int it = 0; it < 4; ++it) {
            int s = it * 256 + t;
            int c = s >> 4;
            int kq = (s & 15) * 4;
            ushort4 o;
            o.x = f2bf(T[kq + 0][c]); o.y = f2bf(T[kq + 1][c]);
            o.z = f2bf(T[kq + 2][c]); o.w = f2bf(T[kq + 3][c]);
            *(ushort4*)(wt + (size_t)(m * 256 + c0 + c) * 256 + k0 + kq) = o;
        }
        if (kt == 0 && t < 64) bcat[m * 256 + c0 + t] = B[c0 + t];
    } else if (bid < 1088) {
        int i = (bid - 64) * 256 + t;
        const int stride = 1024 * 256;
        for (; i < e; i += stride)
            pos[i] = atomicAdd(&deg[dst[i]], 1);
    } else {
        int i = (bid - 1088) * 256 + t;
        const int stride = 2048 * 256;
        for (; i < total4; i += stride) {
            float4 v = ((const float4*)x)[i];
            ushort4 o;
            o.x = f2bf(v.x); o.y = f2bf(v.y); o.z = f2bf(v.z); o.w = f2bf(v.w);
            ((ushort4*)xb)[i] = o;
        }
    }
}

// ---------------------------------------------------------------------------
// MFMA GEMM: 128x128 tile, 4 waves each 64x64 (4x4 frags). Grid (n/128, 8).
// Outputs: msel 0 qarr, 1/2 kv packed, 3 skip.
// ---------------------------------------------------------------------------
__global__ __launch_bounds__(256) void la_gemm_mfma(
    const unsigned short* __restrict__ xb, const unsigned short* __restrict__ wt,
    const float* __restrict__ bcat,
    unsigned short* __restrict__ qarr, unsigned short* __restrict__ kv,
    unsigned short* __restrict__ skiparr, int n)
{
    __shared__ __align__(16) unsigned short As[128 * 40];
    __shared__ __align__(16) unsigned short Bs[128 * 40];

    const int row0 = blockIdx.x * 128;
    const int col0 = blockIdx.y * 128;
    const int msel = blockIdx.y >> 1;
    const int t = threadIdx.x;
    const int l = t & 63;
    const int w = t >> 6;
    const int wr = w >> 1, wc = w & 1;
    const int l15 = l & 15, l4 = l >> 4;

    f32x4 acc[4][4];
#pragma unroll
    for (int i = 0; i < 4; ++i)
#pragma unroll
        for (int j = 0; j < 4; ++j) acc[i][j] = (f32x4){0.f, 0.f, 0.f, 0.f};

    for (int k0 = 0; k0 < 256; k0 += 32) {
#pragma unroll
        for (int c2 = 0; c2 < 2; ++c2) {
            int chunk = t + c2 * 256;
            int r  = chunk >> 2;
            int ko = (chunk & 3) * 8;
            int ga = row0 + r;
            s16x8 va = (s16x8){0,0,0,0,0,0,0,0};
            if (ga < n) va = *(const s16x8*)(xb + (size_t)ga * 256 + k0 + ko);
            *(s16x8*)(As + r * 40 + ko) = va;
            int gb = col0 + r;
            s16x8 vb = *(const s16x8*)(wt + (size_t)gb * 256 + k0 + ko);
            *(s16x8*)(Bs + r * 40 + ko) = vb;
        }
        __syncthreads();
        s16x8 af[4], bfr[4];
#pragma unroll
        for (int f = 0; f < 4; ++f) {
            af[f]  = *(const s16x8*)(As + (wr * 64 + f * 16 + l15) * 40 + l4 * 8);
            bfr[f] = *(const s16x8*)(Bs + (wc * 64 + f * 16 + l15) * 40 + l4 * 8);
        }
#pragma unroll
        for (int fm = 0; fm < 4; ++fm)
#pragma unroll
            for (int fn = 0; fn < 4; ++fn)
                acc[fm][fn] = __builtin_amdgcn_mfma_f32_16x16x32_bf16(
                    af[fm], bfr[fn], acc[fm][fn], 0, 0, 0);
        __syncthreads();
    }

#pragma unroll
    for (int fm = 0; fm < 4; ++fm) {
#pragma unroll
        for (int fn = 0; fn < 4; ++fn) {
            int gc = col0 + wc * 64 + fn * 16 + l15;
            int c  = gc & 255;
            float bb = bcat[gc];
#pragma unroll
            for (int j = 0; j < 4; ++j) {
                int gr = row0 + wr * 64 + fm * 16 + l4 * 4 + j;
                if (gr >= n) continue;
                unsigned short val = f2bf(acc[fm][fn][j] + bb);
                if (msel == 0) {
                    qarr[(size_t)gr * 256 + c] = val;
                } else if (msel == 3) {
                    skiparr[(size_t)gr * 256 + c] = val;
                } else {
                    int hh = c >> 6, ch = c & 63;
                    size_t idx = (size_t)gr * 512 + hh * 128 + (ch >> 2) * 8
                               + (ch & 3) + ((msel == 2) ? 4 : 0);
                    kv[idx] = val;
                }
            }
        }
    }
}

// ---------------------------------------------------------------------------
// Scan: chunk sums; final kernel derives its own chunk-base by reducing part.
// ---------------------------------------------------------------------------
__global__ void la_chunksum(const int* __restrict__ deg, int n, int* __restrict__ part)
{
    int b = blockIdx.x, t = threadIdx.x;
    int i = b * 256 + t;
    int v = (i < n) ? deg[i] : 0;
#pragma unroll
    for (int mask = 32; mask >= 1; mask >>= 1) v += __shfl_xor(v, mask);
    __shared__ int ws[4];
    if ((t & 63) == 0) ws[t >> 6] = v;
    __syncthreads();
    if (t == 0) part[b] = ws[0] + ws[1] + ws[2] + ws[3];
}

__global__ void la_scanfinal(const int* __restrict__ deg, int n,
                             const int* __restrict__ part, int* __restrict__ offs,
                             int e)
{
    int b = blockIdx.x, t = threadIdx.x;
    // base = sum(part[0..b-1])  (nchunk <= 256, so part[t] covers it)
    int pv = (t < b) ? part[t] : 0;
#pragma unroll
    for (int mask = 32; mask >= 1; mask >>= 1) pv += __shfl_xor(pv, mask);
    __shared__ int pws[4];
    if ((t & 63) == 0) pws[t >> 6] = pv;
    __syncthreads();
    const int base = pws[0] + pws[1] + pws[2] + pws[3];

    int i = b * 256 + t;
    int d = (i < n) ? deg[i] : 0;
    int v = d;
#pragma unroll
    for (int o = 1; o < 64; o <<= 1) {
        int u = __shfl_up(v, o);
        if ((t & 63) >= o) v += u;
    }
    __shared__ int wt[4];
    if ((t & 63) == 63) wt[t >> 6] = v;
    __syncthreads();
    int add = 0;
    for (int wv = 0; wv < (t >> 6); ++wv) add += wt[wv];
    int excl = v + add - d + base;
    if (i < n) offs[i] = excl;
    if (b == 0 && t == 0) offs[n] = e;
}

// ---------------------------------------------------------------------------
// Scatter, atomic-free: final slot = offs[dst] + pos (rank from la_prep).
// ---------------------------------------------------------------------------
__global__ void la_scatter2(const int* __restrict__ src, const int* __restrict__ dst,
                            const float* __restrict__ ea,
                            const int* __restrict__ pos,
                            const int* __restrict__ offs, int e,
                            uint2* __restrict__ rec)
{
    int i = blockIdx.x * blockDim.x + threadIdx.x;
    int stride = gridDim.x * blockDim.x;
    for (; i < e; i += stride) {
        int d = dst[i];
        int p = offs[d] + pos[i];
        rec[p] = make_uint2((unsigned int)src[i], __float_as_uint(ea[i]));
    }
}

// ---------------------------------------------------------------------------
// Attention v4: block = node, wave = head, 16-lane quarters, 4 ch/lane.
// 2x unrolled: each quarter processes edges j and j+4 per iteration with
// independent partial accumulators (no online max -> sums are associative).
// ---------------------------------------------------------------------------
__global__ __launch_bounds__(256) void la_attn4(
    const unsigned short* __restrict__ qarr,
    const unsigned short* __restrict__ kv,
    const unsigned short* __restrict__ skiparr,
    const uint2* __restrict__ rec,
    const int* __restrict__ offs,
    const float* __restrict__ We, const float* __restrict__ be,
    unsigned short* __restrict__ outb)
{
    const int node = blockIdx.x;
    const int t = threadIdx.x;
    const int h = t >> 6;
    const int l = t & 63;
    const int quarter = l >> 4;
    const int lc = l & 15;
    const int cb = h * 64 + lc * 4;

    uint2 qp = *(const uint2*)(qarr + (size_t)node * 256 + cb);
    const float q0 = blo(qp.x), q1 = bhi(qp.x);
    const float q2 = blo(qp.y), q3 = bhi(qp.y);
    float4 we4 = *(const float4*)(We + cb);
    float4 be4 = *(const float4*)(be + cb);

    float pw = fmaf(q3, we4.w, fmaf(q2, we4.z, fmaf(q1, we4.y, q0 * we4.x)));
    float pb = fmaf(q3, be4.w, fmaf(q2, be4.z, fmaf(q1, be4.y, q0 * be4.x)));
#pragma unroll
    for (int mask = 1; mask <= 8; mask <<= 1) {
        pw += __shfl_xor(pw, mask);
        pb += __shfl_xor(pb, mask);
    }
    const float qWe8 = pw * LOG2E_8;
    const float qbe8 = pb * LOG2E_8;

    const int start = offs[node], end = offs[node + 1];
    const int koff = h * 128 + lc * 8;

    float lsA = 0.f, SfA = 0.f, a0A = 0.f, a1A = 0.f, a2A = 0.f, a3A = 0.f;
    float lsB = 0.f, SfB = 0.f, a0B = 0.f, a1B = 0.f, a2B = 0.f, a3B = 0.f;

    for (int j0 = start; j0 < end; j0 += 8) {
        int ja = j0 + quarter;
        int jb = j0 + 4 + quarter;
        bool va = (ja < end), vb = (jb < end);
        int jja = va ? ja : j0;
        int jjb = vb ? jb : j0;
        uint2 ra = rec[jja];
        uint2 rb = rec[jjb];
        uint4 kva = *(const uint4*)(kv + (((size_t)(int)ra.x) << 9) + koff);
        uint4 kvb = *(const uint4*)(kv + (((size_t)(int)rb.x) << 9) + koff);
        float eaa = __uint_as_float(ra.y);
        float eab = __uint_as_float(rb.y);

        float da = fmaf(q3, bhi(kva.y), fmaf(q2, blo(kva.y),
                   fmaf(q1, bhi(kva.x), q0 * blo(kva.x))));
        float db = fmaf(q3, bhi(kvb.y), fmaf(q2, blo(kvb.y),
                   fmaf(q1, bhi(kvb.x), q0 * blo(kvb.x))));
#pragma unroll
        for (int mask = 1; mask <= 8; mask <<= 1) {
            da += __shfl_xor(da, mask);
            db += __shfl_xor(db, mask);
        }
        float aLa = fmaf(da, LOG2E_8, fmaf(eaa, qWe8, qbe8));
        float aLb = fmaf(db, LOG2E_8, fmaf(eab, qWe8, qbe8));
        aLa = va ? aLa : -INFINITY;
        aLb = vb ? aLb : -INFINITY;
        float fa = exp2f(aLa);
        float fb = exp2f(aLb);

        lsA += fa;               lsB += fb;
        SfA = fmaf(fa, eaa, SfA); SfB = fmaf(fb, eab, SfB);
        a0A = fmaf(fa, blo(kva.z), a0A); a0B = fmaf(fb, blo(kvb.z), a0B);
        a1A = fmaf(fa, bhi(kva.z), a1A); a1B = fmaf(fb, bhi(kvb.z), a1B);
        a2A = fmaf(fa, blo(kva.w), a2A); a2B = fmaf(fb, blo(kvb.w), a2B);
        a3A = fmaf(fa, bhi(kva.w), a3A); a3B = fmaf(fb, bhi(kvb.w), a3B);
    }

    float lsum = lsA + lsB, Sfa = SfA + SfB;
    float a0 = a0A + a0B, a1 = a1A + a1B, a2 = a2A + a2B, a3 = a3A + a3B;

#pragma unroll
    for (int mask = 16; mask <= 32; mask <<= 1) {
        lsum += __shfl_xor(lsum, mask);
        Sfa  += __shfl_xor(Sfa,  mask);
        a0   += __shfl_xor(a0,   mask);
        a1   += __shfl_xor(a1,   mask);
        a2   += __shfl_xor(a2,   mask);
        a3   += __shfl_xor(a3,   mask);
    }

    if (quarter == 0) {
        float inv = 1.f / (lsum + 1e-16f);
        uint2 sp = *(const uint2*)(skiparr + (size_t)node * 256 + cb);
        ushort4 o;
        o.x = f2bf(fmaf(we4.x, Sfa, fmaf(be4.x, lsum, a0)) * inv + blo(sp.x));
        o.y = f2bf(fmaf(we4.y, Sfa, fmaf(be4.y, lsum, a1)) * inv + bhi(sp.x));
        o.z = f2bf(fmaf(we4.z, Sfa, fmaf(be4.z, lsum, a2)) * inv + blo(sp.y));
        o.w = f2bf(fmaf(we4.w, Sfa, fmaf(be4.w, lsum, a3)) * inv + bhi(sp.y));
        *(ushort4*)(outb + (size_t)node * 256 + cb) = o;
    }
}

// ---------------------------------------------------------------------------
// GraphNorm column sums (bf16 input).
// ---------------------------------------------------------------------------
__global__ __launch_bounds__(256) void la_colsum(
    const unsigned short* __restrict__ outb, float* __restrict__ cs,
    float* __restrict__ cs2, int n)
{
    const int col = threadIdx.x;
    const int r0 = blockIdx.x * 64;
    const int rend = (r0 + 64 < n) ? r0 + 64 : n;
    float s = 0.f, s2 = 0.f;
    for (int r = r0; r < rend; ++r) {
        float vv = bf2f(outb[(size_t)r * 256 + col]);
        s += vv;
        s2 = fmaf(vv, vv, s2);
    }
    atomicAdd(&cs[col], s);
    atomicAdd(&cs2[col], s2);
}

// ---------------------------------------------------------------------------
// Gram via MFMA (bf16 input, in-block GraphNorm coeffs): xt = R^T R,
// R = relu(out*A + B). Grid = 3*KSPLIT; tile = bx%3.
// ---------------------------------------------------------------------------
__global__ __launch_bounds__(256) void la_gram_mfma(
    const unsigned short* __restrict__ outb,
    const float* __restrict__ cs, const float* __restrict__ cs2,
    const float* __restrict__ gnw, const float* __restrict__ gnb,
    const float* __restrict__ gms,
    float* __restrict__ xt, int n, int kchunk)
{
    __shared__ __align__(16) unsigned int Ta[128 * 20];
    __shared__ __align__(16) unsigned int Tb[128 * 20];

    const int bx = blockIdx.x;
    const int kc   = bx / 3;
    const int tile = bx - kc * 3;              // 0,1,2
    const int i0 = (tile == 2) ? 128 : 0;
    const int j0 = (tile == 0) ? 0 : 128;
    const bool diag = (tile != 1);
    const int kbeg = kc * kchunk;
    if (kbeg >= n) return;
    const int kend = (kbeg + kchunk < n) ? kbeg + kchunk : n;

    const int t = threadIdx.x;
    const int l = t & 63, w = t >> 6;
    const int wr = w >> 1, wc = w & 1;
    const int l15 = l & 15, l4 = l >> 4;

    const int kp  = t >> 4;
    const int cg8 = t & 15;

    const float invn = 1.f / (float)n;
    float Ai[8], Bi[8], Aj[8], Bj[8];
#pragma unroll
    for (int j = 0; j < 8; ++j) {
        {
            int ci = i0 + cg8 * 8 + j;
            float mean = cs[ci] * invn;
            float m2   = cs2[ci] * invn;
            float s    = gms[ci];
            float var  = m2 - 2.f * s * mean * mean + s * s * mean * mean;
            float a    = gnw[ci] / sqrtf(var + 1e-5f);
            Ai[j] = a; Bi[j] = gnb[ci] - s * mean * a;
        }
        {
            int cj = j0 + cg8 * 8 + j;
            float mean = cs[cj] * invn;
            float m2   = cs2[cj] * invn;
            float s    = gms[cj];
            float var  = m2 - 2.f * s * mean * mean + s * s * mean * mean;
            float a    = gnw[cj] / sqrtf(var + 1e-5f);
            Aj[j] = a; Bj[j] = gnb[cj] - s * mean * a;
        }
    }

    f32x4 acc[4][4];
#pragma unroll
    for (int i = 0; i < 4; ++i)
#pragma unroll
        for (int j = 0; j < 4; ++j) acc[i][j] = (f32x4){0.f, 0.f, 0.f, 0.f};

    const int nsteps = (kend - kbeg + 31) >> 5;
    for (int ks = 0; ks < nsteps; ++ks) {
        const int gr0 = kbeg + ks * 32 + kp * 2;
        const bool v0 = (gr0 < kend), v1 = (gr0 + 1 < kend);

        {
            uint4 u0 = make_uint4(0,0,0,0), u1 = make_uint4(0,0,0,0);
            if (v0) u0 = *(const uint4*)(outb + (size_t)gr0 * 256 + i0 + cg8 * 8);
            if (v1) u1 = *(const uint4*)(outb + (size_t)(gr0+1) * 256 + i0 + cg8 * 8);
            float xs[8] = {blo(u0.x),bhi(u0.x),blo(u0.y),bhi(u0.y),
                           blo(u0.z),bhi(u0.z),blo(u0.w),bhi(u0.w)};
            float ys[8] = {blo(u1.x),bhi(u1.x),blo(u1.y),bhi(u1.y),
                           blo(u1.z),bhi(u1.z),blo(u1.w),bhi(u1.w)};
#pragma unroll
            for (int j = 0; j < 8; ++j) {
                float r0 = v0 ? fmaxf(fmaf(xs[j], Ai[j], Bi[j]), 0.f) : 0.f;
                float r1 = v1 ? fmaxf(fmaf(ys[j], Ai[j], Bi[j]), 0.f) : 0.f;
                int c = cg8 * 8 + j;
                unsigned int u = (unsigned int)f2bf(r0)
                               | ((unsigned int)f2bf(r1) << 16);
                Ta[c * 20 + (kp ^ (((c >> 3) & 3) << 2))] = u;
            }
        }
        if (!diag) {
            uint4 u0 = make_uint4(0,0,0,0), u1 = make_uint4(0,0,0,0);
            if (v0) u0 = *(const uint4*)(outb + (size_t)gr0 * 256 + j0 + cg8 * 8);
            if (v1) u1 = *(const uint4*)(outb + (size_t)(gr0+1) * 256 + j0 + cg8 * 8);
            float xs[8] = {blo(u0.x),bhi(u0.x),blo(u0.y),bhi(u0.y),
                           blo(u0.z),bhi(u0.z),blo(u0.w),bhi(u0.w)};
            float ys[8] = {blo(u1.x),bhi(u1.x),blo(u1.y),bhi(u1.y),
                           blo(u1.z),bhi(u1.z),blo(u1.w),bhi(u1.w)};
#pragma unroll
            for (int j = 0; j < 8; ++j) {
                float r0 = v0 ? fmaxf(fmaf(xs[j], Aj[j], Bj[j]), 0.f) : 0.f;
                float r1 = v1 ? fmaxf(fmaf(ys[j], Aj[j], Bj[j]), 0.f) : 0.f;
                int c = cg8 * 8 + j;
                unsigned int u = (unsigned int)f2bf(r0)
                               | ((unsigned int)f2bf(r1) << 16);
                Tb[c * 20 + (kp ^ (((c >> 3) & 3) << 2))] = u;
            }
        }
        __syncthreads();

        const unsigned int* TB = diag ? Ta : Tb;
        s16x8 af[4], bfr[4];
#pragma unroll
        for (int f = 0; f < 4; ++f) {
            int ca = wr * 64 + f * 16 + l15;
            af[f] = *(const s16x8*)(Ta + ca * 20 + ((l4 * 4) ^ (((ca >> 3) & 3) << 2)));
            int cb2 = wc * 64 + f * 16 + l15;
            bfr[f] = *(const s16x8*)(TB + cb2 * 20 + ((l4 * 4) ^ (((cb2 >> 3) & 3) << 2)));
        }
#pragma unroll
        for (int fm = 0; fm < 4; ++fm)
#pragma unroll
            for (int fn = 0; fn < 4; ++fn)
                acc[fm][fn] = __builtin_amdgcn_mfma_f32_16x16x32_bf16(
                    af[fm], bfr[fn], acc[fm][fn], 0, 0, 0);
        __syncthreads();
    }

#pragma unroll
    for (int fm = 0; fm < 4; ++fm)
#pragma unroll
        for (int fn = 0; fn < 4; ++fn) {
            int col = j0 + wc * 64 + fn * 16 + l15;
#pragma unroll
            for (int j = 0; j < 4; ++j) {
                int row = i0 + wr * 64 + fm * 16 + l4 * 4 + j;
                float vv = acc[fm][fn][j];
                atomicAdd(&xt[(size_t)row * 256 + col], vv);
                if (tile == 1)
                    atomicAdd(&xt[(size_t)col * 256 + row], vv);
            }
        }
}

// ---------------------------------------------------------------------------
// min/max partials (32 blocks), final reduce folded into la_norm prologue.
// ---------------------------------------------------------------------------
__global__ __launch_bounds__(256) void la_minmax_part(
    const float* __restrict__ xt, float* __restrict__ mmp)
{
    const int b = blockIdx.x, t = threadIdx.x;
    float mn = INFINITY, mx = -INFINITY;
#pragma unroll
    for (int k = 0; k < 2; ++k) {
        float4 v = ((const float4*)xt)[b * 512 + k * 256 + t];
        mn = fminf(mn, fminf(fminf(v.x, v.y), fminf(v.z, v.w)));
        mx = fmaxf(mx, fmaxf(fmaxf(v.x, v.y), fmaxf(v.z, v.w)));
    }
#pragma unroll
    for (int mask = 32; mask >= 1; mask >>= 1) {
        mn = fminf(mn, __shfl_xor(mn, mask));
        mx = fmaxf(mx, __shfl_xor(mx, mask));
    }
    __shared__ float smn[4], smx[4];
    if ((t & 63) == 0) { smn[t >> 6] = mn; smx[t >> 6] = mx; }
    __syncthreads();
    if (t == 0) {
        mn = fminf(fminf(smn[0], smn[1]), fminf(smn[2], smn[3]));
        mx = fmaxf(fmaxf(smx[0], smx[1]), fmaxf(smx[2], smx[3]));
        mmp[b * 2]     = mn;
        mmp[b * 2 + 1] = mx;
    }
}

__global__ void la_norm(float* __restrict__ xt, const float* __restrict__ mmp)
{
    float mn = INFINITY, mx = -INFINITY;
#pragma unroll
    for (int i = 0; i < 32; ++i) {
        mn = fminf(mn, mmp[i * 2]);
        mx = fmaxf(mx, mmp[i * 2 + 1]);
    }
    float inv = 1.f / (mx - mn + 1e-8f);
    int i = blockIdx.x * blockDim.x + threadIdx.x;
    xt[i] = (xt[i] - mn) * inv;
}

// ---------------------------------------------------------------------------
extern "C" void kernel_launch(void* const* d_in, const int* in_sizes, int n_in,
                              void* d_out, int out_size, void* d_ws, size_t ws_size,
                              hipStream_t stream)
{
    const float* x   = (const float*)d_in[0];
    const int*   ei  = (const int*)  d_in[1];
    const float* ea  = (const float*)d_in[2];
    const float* Wq  = (const float*)d_in[3];
    const float* bq  = (const float*)d_in[4];
    const float* Wk  = (const float*)d_in[5];
    const float* bk  = (const float*)d_in[6];
    const float* Wv  = (const float*)d_in[7];
    const float* bv  = (const float*)d_in[8];
    const float* We  = (const float*)d_in[9];
    const float* be  = (const float*)d_in[10];
    const float* Ws  = (const float*)d_in[11];
    const float* bs  = (const float*)d_in[12];
    const float* gnw = (const float*)d_in[13];
    const float* gnb = (const float*)d_in[14];
    const float* gms = (const float*)d_in[15];

    const int n = in_sizes[0] / 256;
    const int e = in_sizes[1] / 2;
    const int* srcI = ei;
    const int* dstI = ei + e;

    char* ws = (char*)d_ws;
    size_t off = 0;
    auto take = [&](size_t bytes) -> void* {
        void* p = (void*)(ws + off);
        off += (bytes + 255) & ~(size_t)255;
        return p;
    };
    // zero-region: deg | cs | cs2 contiguous -> ONE memset
    int*   deg    = (int*)  take((size_t)n * 4);
    float* cs     = (float*)take(256 * 4);
    float* cs2    = (float*)take(256 * 4);
    size_t zero_bytes = off;

    unsigned short* xb    = (unsigned short*)take((size_t)n * 256 * 2);
    unsigned short* wtbuf = (unsigned short*)take((size_t)1024 * 256 * 2);
    float*          bcat  = (float*)take(1024 * 4);
    unsigned short* qarr  = (unsigned short*)take((size_t)n * 256 * 2);
    unsigned short* kv    = (unsigned short*)take((size_t)n * 512 * 2);
    unsigned short* skipb = (unsigned short*)take((size_t)n * 256 * 2);
    unsigned short* outb  = (unsigned short*)take((size_t)n * 256 * 2);
    int*   pos    = (int*)  take((size_t)e * 4);
    int*   offs   = (int*)  take((size_t)(n + 1) * 4);
    int*   part   = (int*)  take(256 * 4);
    uint2* csrR   = (uint2*)take((size_t)e * 8);
    float* mmp    = (float*)take(64 * 4);
    (void)ws_size; (void)n_in; (void)out_size;

    float* xt = (float*)d_out;

    hipMemsetAsync(deg, 0, zero_bytes, stream);
    hipMemsetAsync(xt,  0, (size_t)65536 * 4, stream);

    la_prep<<<3136, 256, 0, stream>>>(x, n * 64,
                                      Wq, Wk, Wv, Ws, bq, bk, bv, bs,
                                      wtbuf, bcat, dstI, e, deg, pos, xb);

    dim3 gg((n + 127) / 128, 8);
    la_gemm_mfma<<<gg, 256, 0, stream>>>(xb, wtbuf, bcat, qarr, kv, skipb, n);

    const int nchunk = (n + 255) / 256;
    la_chunksum <<<nchunk, 256, 0, stream>>>(deg, n, part);
    la_scanfinal<<<nchunk, 256, 0, stream>>>(deg, n, part, offs, e);
    la_scatter2 <<<1024, 256, 0, stream>>>(srcI, dstI, ea, pos, offs, e, csrR);

    la_attn4<<<n, 256, 0, stream>>>(qarr, kv, skipb, csrR, offs, We, be, outb);

    la_colsum<<<(n + 63) / 64, 256, 0, stream>>>(outb, cs, cs2, n);

    const int KSPLIT = 128;
    int kchunk = ((n + KSPLIT - 1) / KSPLIT + 31) & ~31;
    la_gram_mfma<<<3 * KSPLIT, 256, 0, stream>>>(outb, cs, cs2, gnw, gnb, gms,
                                                 xt, n, kchunk);

    la_minmax_part<<<32, 256, 0, stream>>>(xt, mmp);
    la_norm<<<256, 256, 0, stream>>>(xt, mmp);
}